// Round 3
// baseline (552.344 us; speedup 1.0000x reference)
//
#include <hip/hip_runtime.h>
#include <cstdint>
#include <cstddef>

// ---- sizes (compile-time for this problem) ----
#define S_  1024
#define B_  8
#define D_  1024
#define H_  16
#define HD_ 64
#define DFF_ 4096
#define M_  (S_*B_)      // 8192 rows
#define QKV_N (3*D_)     // 3072

typedef float f32x4 __attribute__((ext_vector_type(4)));
typedef __bf16 bf16x8 __attribute__((ext_vector_type(8)));
typedef __bf16 bf16x4 __attribute__((ext_vector_type(4)));

#define GLDS16(gp, lp) __builtin_amdgcn_global_load_lds( \
    (__attribute__((address_space(1))) void*)(gp), \
    (__attribute__((address_space(3))) void*)(lp), 16, 0, 0)

// ---------------------------------------------------------------------------
// fused fp32 -> bf16 conversion of all 5 tensors in one launch
// ---------------------------------------------------------------------------
#define CB0 (M_*D_/4)
#define CB1 (CB0 + QKV_N*D_/4)
#define CB2 (CB1 + D_*D_/4)
#define CB3 (CB2 + DFF_*D_/4)
#define CB4 (CB3 + D_*DFF_/4)

__global__ __launch_bounds__(256)
void cvt_all(const float* __restrict__ src, const float* __restrict__ w1f,
             const float* __restrict__ w2f, const float* __restrict__ w3f,
             const float* __restrict__ w4f,
             __bf16* __restrict__ src_bf, __bf16* __restrict__ w1,
             __bf16* __restrict__ w2, __bf16* __restrict__ w3,
             __bf16* __restrict__ w4)
{
    int i = blockIdx.x * 256 + threadIdx.x;
    const float* in; __bf16* out; int off;
    if      (i < CB0) { in = src; out = src_bf; off = 0;   }
    else if (i < CB1) { in = w1f; out = w1;     off = CB0; }
    else if (i < CB2) { in = w2f; out = w2;     off = CB1; }
    else if (i < CB3) { in = w3f; out = w3;     off = CB2; }
    else if (i < CB4) { in = w4f; out = w4;     off = CB3; }
    else return;
    int j = i - off;
    float4 v = *(const float4*)(in + (size_t)j * 4);
    __bf16 t[4] = {(__bf16)v.x, (__bf16)v.y, (__bf16)v.z, (__bf16)v.w};
    *(uint2*)(out + (size_t)j * 4) = *(uint2*)t;
}

// ---------------------------------------------------------------------------
// GEMM: C = A[M,K]*W[N,K]^T (+bias). 256x256 tile, BK=32, 8 waves (2x4),
// 3-deep LDS ring pipeline (96KB dynamic LDS), counted vmcnt, raw s_barrier.
// Chunked XCD raster + source-side LDS swizzle + j-inner C store (round 2).
// ---------------------------------------------------------------------------
template<bool OUT_BF16, bool RELU, bool ADD_BIAS, bool SPLITZ>
__global__ __launch_bounds__(512, 2)
void gemm256(const __bf16* __restrict__ A, const __bf16* __restrict__ W,
             const float* __restrict__ bias,
             void* __restrict__ Cv0, void* __restrict__ Cv1,
             int N, int Kloop, int lda)
{
    extern __shared__ __bf16 lds[];
    __bf16* As = lds;                 // 3 x [256][32] bf16 = 48KB
    __bf16* Bs = lds + 3 * 8192;      // 3 x [256][32] bf16 = 48KB

    const int tid  = threadIdx.x;
    const int lane = tid & 63;
    const int wv   = tid >> 6;          // 0..7
    const int quad = lane >> 4;
    const int l15  = lane & 15;
    const int wm   = (wv >> 2) * 128;   // 0 / 128
    const int wn   = (wv & 3) * 64;     // 0 / 64 / 128 / 192

    // chunked raster + XCD-contiguous assignment (all grids: nwg%32==0, GM%8==0)
    const int id  = blockIdx.y * gridDim.x + blockIdx.x;
    const int nwg = gridDim.x * gridDim.y;
    const int q8  = nwg >> 3;
    const int k   = (id & 7) * q8 + (id >> 3);   // XCD id&7 gets contiguous k
    const int within = k & 31;                    // 0..31 inside chunk
    const int chunk  = k >> 5;
    const int nchm   = gridDim.x >> 3;            // chunk columns (GM/8)
    const int cm     = chunk % nchm;
    const int cn     = chunk / nchm;
    const int m0 = (cm * 8 + (within & 7)) * 256;
    const int n0 = (cn * 4 + (within >> 3)) * 256;

    void* Cv = Cv0;
    if (SPLITZ) {
        const int koff = blockIdx.z * Kloop;
        A += koff;
        W += koff;
        if (blockIdx.z) Cv = Cv1;
    }

    const int nt = Kloop >> 5;          // K-tiles of 32

    // stage one K-tile (A: 256x32, B: 256x32) -> 4 x GLDS16 per thread.
    // LDS dest is linear; the k-slot is pre-swizzled on the global source.
    #define STAGE(kt, buf) do { \
        const int k0s = (kt) << 5; \
        _Pragma("unroll") \
        for (int u = 0; u < 2; ++u) { \
            int c   = u * 512 + tid; \
            int row = c >> 2; \
            int ssl = (c & 3) ^ ((row >> 1) & 3); \
            GLDS16(A + (size_t)(m0 + row) * lda + k0s + ssl * 8, \
                   (char*)(As + (buf) * 8192) + c * 16); \
            GLDS16(W + (size_t)(n0 + row) * lda + k0s + ssl * 8, \
                   (char*)(Bs + (buf) * 8192) + c * 16); \
        } \
    } while (0)

    // prologue: fill 2 pipeline stages
    STAGE(0, 0);
    STAGE(1, 1);
    asm volatile("s_waitcnt vmcnt(4)" ::: "memory");
    __builtin_amdgcn_s_barrier();
    __builtin_amdgcn_sched_barrier(0);

    f32x4 acc[8][4] = {};

    int cur = 0, stg = 2;
    for (int t = 0; t < nt; ++t) {
        if (t + 2 < nt) STAGE(t + 2, stg);

        bf16x8 bf[4], af[8];
        #pragma unroll
        for (int j = 0; j < 4; ++j) {
            int rb = wn + j * 16 + l15;
            bf[j] = *(const bf16x8*)(Bs + cur * 8192 + rb * 32 + (quad ^ ((rb >> 1) & 3)) * 8);
        }
        #pragma unroll
        for (int i = 0; i < 8; ++i) {
            int ra = wm + i * 16 + l15;
            af[i] = *(const bf16x8*)(As + cur * 8192 + ra * 32 + (quad ^ ((ra >> 1) & 3)) * 8);
        }

        __builtin_amdgcn_s_setprio(1);
        #pragma unroll
        for (int i = 0; i < 8; ++i)
            #pragma unroll
            for (int j = 0; j < 4; ++j)
                acc[i][j] = __builtin_amdgcn_mfma_f32_16x16x32_bf16(af[i], bf[j], acc[i][j], 0, 0, 0);
        __builtin_amdgcn_s_setprio(0);

        if (t + 1 < nt) {
            if (t + 2 < nt) { asm volatile("s_waitcnt vmcnt(4)" ::: "memory"); }
            else            { asm volatile("s_waitcnt vmcnt(0)" ::: "memory"); }
            __builtin_amdgcn_s_barrier();
            __builtin_amdgcn_sched_barrier(0);
        }
        if (++cur == 3) cur = 0;
        if (++stg == 3) stg = 0;
    }
    #undef STAGE

    // epilogue: row = m0+wm+i*16+quad*4+r ; col = n0+wn+j*16+l15.
    // j innermost: 4 back-to-back 32B stores complete each 128B line.
    float bvj[4];
    #pragma unroll
    for (int j = 0; j < 4; ++j)
        bvj[j] = ADD_BIAS ? bias[n0 + wn + j * 16 + l15] : 0.f;
    #pragma unroll
    for (int i = 0; i < 8; ++i) {
        const int rbase = m0 + wm + i * 16 + quad * 4;
        #pragma unroll
        for (int r = 0; r < 4; ++r) {
            #pragma unroll
            for (int j = 0; j < 4; ++j) {
                const int col = n0 + wn + j * 16 + l15;
                float v = acc[i][j][r] + bvj[j];
                if (RELU) v = fmaxf(v, 0.f);
                if (OUT_BF16)
                    ((__bf16*)Cv)[(size_t)(rbase + r) * N + col] = (__bf16)v;
                else
                    ((float*)Cv)[(size_t)(rbase + r) * N + col] = v;
            }
        }
    }
}

// ---------------------------------------------------------------------------
// V transpose: qkv V-part -> vt[bh][d][t]
// ---------------------------------------------------------------------------
__global__ __launch_bounds__(256)
void v_transpose(const __bf16* __restrict__ qkv, __bf16* __restrict__ vt)
{
    __shared__ __bf16 T[64 * 65];
    const int tid = threadIdx.x;
    const int t0  = blockIdx.x * 64;
    const int bh  = blockIdx.y;
    const int b   = bh & (B_ - 1);
    const int h   = bh / B_;

    #pragma unroll
    for (int j = 0; j < 2; ++j) {
        int c = j * 256 + tid;
        int i = c >> 3, cc = c & 7;
        const __bf16* g = qkv + (size_t)((t0 + i) * B_ + b) * QKV_N + 2 * D_ + h * HD_ + cc * 8;
        bf16x8 v = *(const bf16x8*)g;
        #pragma unroll
        for (int u = 0; u < 8; ++u) T[(cc * 8 + u) * 65 + i] = v[u];
    }
    __syncthreads();
    #pragma unroll
    for (int j = 0; j < 2; ++j) {
        int c = j * 256 + tid;
        int d = c >> 3, cc = c & 7;
        __bf16 pk[8];
        #pragma unroll
        for (int u = 0; u < 8; ++u) pk[u] = T[d * 65 + cc * 8 + u];
        *(uint4*)(vt + ((size_t)bh * HD_ + d) * S_ + t0 + cc * 8) = *(uint4*)pk;
    }
}

// ---------------------------------------------------------------------------
// Flash attention, S^T formulation.
// Round-3: stride-64 XOR-swizzled LDS (slot16 ^= row&7 -> 2-way max on all
// ds_read_b128 / stage writes), T14 register prefetch of next K/V tile
// (global loads issued before compute, LDS write after the compute-end
// barrier), XCD swizzle kept from round 2. LDS 36->32KB.
// ---------------------------------------------------------------------------
#define AST 64

__global__ __launch_bounds__(256)
void attn_flash(const __bf16* __restrict__ qkv, const __bf16* __restrict__ vt,
                __bf16* __restrict__ out)
{
    __shared__ __bf16 Qs[64 * AST];
    __shared__ __bf16 Ks[64 * AST];
    __shared__ __bf16 Vt[64 * AST];
    __shared__ __bf16 Ps[64 * AST];

    const int tid  = threadIdx.x;
    const int lane = tid & 63;
    const int wv   = tid >> 6;
    const int quad = lane >> 4;
    const int l15  = lane & 15;

    // grid = (16, 128): give each XCD 256 contiguous k -> 16 whole heads per
    // XCD, K/V stays L2-resident.
    const int id = blockIdx.y * gridDim.x + blockIdx.x;
    const int k  = (id & 7) * ((S_ / 64) * B_ * H_ / 8) + (id >> 3);
    const int s0 = (k & 15) * 64;
    const int bh = k >> 4;
    const int b  = bh & (B_ - 1);
    const int h  = bh / B_;

    // stage Q (swizzled): row i, 16B slot cc -> slot cc^(i&7)
    #pragma unroll
    for (int j = 0; j < 2; ++j) {
        int c = j * 256 + tid;
        int i = c >> 3, cc = c & 7;
        const __bf16* g = qkv + (size_t)((s0 + i) * B_ + b) * QKV_N + h * HD_ + cc * 8;
        *(uint4*)(Qs + i * AST + ((cc ^ (i & 7)) * 8)) = *(const uint4*)g;
    }

    // prefetch K/V tile 0 into regs
    uint4 kreg[2], vreg[2];
    #pragma unroll
    for (int j = 0; j < 2; ++j) {
        int c = j * 256 + tid;
        int i = c >> 3, cc = c & 7;
        kreg[j] = *(const uint4*)(qkv + (size_t)((i) * B_ + b) * QKV_N + D_ + h * HD_ + cc * 8);
        vreg[j] = *(const uint4*)(vt + ((size_t)bh * HD_ + i) * S_ + cc * 8);
    }

    f32x4 oacc[4] = {};
    float m_run = -1e30f, l_run = 0.f;
    const float C2    = 0.125f * 1.44269504f;
    const float LOG2E = 1.44269504f;

    for (int t0 = 0; t0 < S_; t0 += 64) {
        // write prefetched K/V to LDS (swizzled)
        #pragma unroll
        for (int j = 0; j < 2; ++j) {
            int c = j * 256 + tid;
            int i = c >> 3, cc = c & 7;
            *(uint4*)(Ks + i * AST + ((cc ^ (i & 7)) * 8)) = kreg[j];
            *(uint4*)(Vt + i * AST + ((cc ^ (i & 7)) * 8)) = vreg[j];
        }
        __syncthreads();

        // issue next tile's global loads (latency hides under compute)
        if (t0 + 64 < S_) {
            const int t1 = t0 + 64;
            #pragma unroll
            for (int j = 0; j < 2; ++j) {
                int c = j * 256 + tid;
                int i = c >> 3, cc = c & 7;
                kreg[j] = *(const uint4*)(qkv + (size_t)((t1 + i) * B_ + b) * QKV_N + D_ + h * HD_ + cc * 8);
                vreg[j] = *(const uint4*)(vt + ((size_t)bh * HD_ + i) * S_ + t1 + cc * 8);
            }
        }

        // QK^T (S^T: lane holds 16 k's for q = wv*16+l15)
        f32x4 sacc[4] = {};
        const int qrow = wv * 16 + l15;
        #pragma unroll
        for (int kk = 0; kk < 2; ++kk) {
            bf16x8 bq = *(const bf16x8*)(Qs + qrow * AST + (((kk * 4 + quad) ^ (qrow & 7)) * 8));
            #pragma unroll
            for (int j = 0; j < 4; ++j) {
                int krow = j * 16 + l15;
                bf16x8 ak = *(const bf16x8*)(Ks + krow * AST + (((kk * 4 + quad) ^ (krow & 7)) * 8));
                sacc[j] = __builtin_amdgcn_mfma_f32_16x16x32_bf16(ak, bq, sacc[j], 0, 0, 0);
            }
        }

        float mx = sacc[0][0];
        #pragma unroll
        for (int j = 0; j < 4; ++j)
            #pragma unroll
            for (int r = 0; r < 4; ++r) mx = fmaxf(mx, sacc[j][r]);
        mx = fmaxf(mx, __shfl_xor(mx, 16, 64));
        mx = fmaxf(mx, __shfl_xor(mx, 32, 64));
        float mnew = fmaxf(m_run, mx * 0.125f);
        float k1 = mnew * LOG2E;
        float rs = 0.f;
        #pragma unroll
        for (int j = 0; j < 4; ++j)
            #pragma unroll
            for (int r = 0; r < 4; ++r) {
                float p = __builtin_amdgcn_exp2f(sacc[j][r] * C2 - k1);
                sacc[j][r] = p;
                rs += p;
            }
        rs += __shfl_xor(rs, 16, 64);
        rs += __shfl_xor(rs, 32, 64);
        float alpha = __builtin_amdgcn_exp2f((m_run - mnew) * LOG2E);
        l_run = l_run * alpha + rs;
        m_run = mnew;

        // P write (swizzled): logical col j*16+quad*4 -> 16B slot j*2+(quad>>1),
        // 8B half quad&1
        #pragma unroll
        for (int j = 0; j < 4; ++j) {
            __bf16 pk[4] = {(__bf16)sacc[j][0], (__bf16)sacc[j][1],
                            (__bf16)sacc[j][2], (__bf16)sacc[j][3]};
            int s16 = (j * 2 + (quad >> 1)) ^ (qrow & 7);
            *(uint2*)(Ps + qrow * AST + s16 * 8 + (quad & 1) * 4) = *(uint2*)pk;
        }

        #pragma unroll
        for (int r = 0; r < 4; ++r) {
            float ar = __shfl(alpha, quad * 4 + r, 64);
            #pragma unroll
            for (int jd = 0; jd < 4; ++jd) oacc[jd][r] *= ar;
        }

        // PV
        #pragma unroll
        for (int kk = 0; kk < 2; ++kk) {
            bf16x8 ap = *(const bf16x8*)(Ps + qrow * AST + (((kk * 4 + quad) ^ (qrow & 7)) * 8));
            #pragma unroll
            for (int jd = 0; jd < 4; ++jd) {
                int vrow = jd * 16 + l15;
                bf16x8 bv = *(const bf16x8*)(Vt + vrow * AST + (((kk * 4 + quad) ^ (vrow & 7)) * 8));
                oacc[jd] = __builtin_amdgcn_mfma_f32_16x16x32_bf16(ap, bv, oacc[jd], 0, 0, 0);
            }
        }
        __syncthreads();   // all K/V reads done; next iter overwrites
    }

    float linv = 1.f / l_run;
    #pragma unroll
    for (int r = 0; r < 4; ++r) {
        float lr = __shfl(linv, quad * 4 + r, 64);
        int s = s0 + wv * 16 + quad * 4 + r;
        #pragma unroll
        for (int jd = 0; jd < 4; ++jd) {
            int d = jd * 16 + l15;
            out[(size_t)(s * B_ + b) * D_ + h * HD_ + d] = (__bf16)(oacc[jd][r] * lr);
        }
    }
}

// ---------------------------------------------------------------------------
// LayerNorm( xa + p0 + p1 + bias[col] ) * g + beta -> yout fp32 (+ ybf bf16)
// ---------------------------------------------------------------------------
__global__ __launch_bounds__(256)
void ln_res3(const float* __restrict__ xa, const __bf16* __restrict__ p0,
             const __bf16* __restrict__ p1, const float* __restrict__ bias,
             const float* __restrict__ g, const float* __restrict__ beta,
             float* __restrict__ yout, __bf16* __restrict__ ybf)
{
    __shared__ float red[8];
    const int row = blockIdx.x;
    const int tid = threadIdx.x;
    const size_t base = (size_t)row * D_ + tid * 4;

    float4 a  = *(const float4*)(xa + base);
    bf16x4 q0 = *(const bf16x4*)(p0 + base);
    bf16x4 q1 = *(const bf16x4*)(p1 + base);
    float4 bb = *(const float4*)(bias + tid * 4);
    float x0 = a.x + (float)q0[0] + (float)q1[0] + bb.x;
    float x1 = a.y + (float)q0[1] + (float)q1[1] + bb.y;
    float x2 = a.z + (float)q0[2] + (float)q1[2] + bb.z;
    float x3 = a.w + (float)q0[3] + (float)q1[3] + bb.w;

    float s  = x0 + x1 + x2 + x3;
    float ss = x0 * x0 + x1 * x1 + x2 * x2 + x3 * x3;
    for (int msk = 1; msk <= 32; msk <<= 1) {
        s  += __shfl_xor(s,  msk, 64);
        ss += __shfl_xor(ss, msk, 64);
    }
    const int wv = tid >> 6;
    if ((tid & 63) == 0) { red[wv] = s; red[4 + wv] = ss; }
    __syncthreads();
    s  = red[0] + red[1] + red[2] + red[3];
    ss = red[4] + red[5] + red[6] + red[7];
    float mean = s * (1.f / D_);
    float var  = ss * (1.f / D_) - mean * mean;
    float rstd = rsqrtf(var + 1e-5f);

    float4 gv = *(const float4*)(g + tid * 4);
    float4 bv = *(const float4*)(beta + tid * 4);
    float y0 = (x0 - mean) * rstd * gv.x + bv.x;
    float y1 = (x1 - mean) * rstd * gv.y + bv.y;
    float y2 = (x2 - mean) * rstd * gv.z + bv.z;
    float y3 = (x3 - mean) * rstd * gv.w + bv.w;
    *(float4*)(yout + base) = make_float4(y0, y1, y2, y3);
    if (ybf) {
        __bf16 t[4] = {(__bf16)y0, (__bf16)y1, (__bf16)y2, (__bf16)y3};
        *(uint2*)(ybf + base) = *(uint2*)t;
    }
}

// ---------------------------------------------------------------------------
extern "C" void kernel_launch(void* const* d_in, const int* in_sizes, int n_in,
                              void* d_out, int out_size, void* d_ws, size_t ws_size,
                              hipStream_t stream)
{
    const float* src       = (const float*)d_in[0];
    const float* in_proj_w = (const float*)d_in[1];
    const float* in_proj_b = (const float*)d_in[2];
    const float* out_w     = (const float*)d_in[3];
    const float* out_b     = (const float*)d_in[4];
    const float* lin1_w    = (const float*)d_in[5];
    const float* lin1_b    = (const float*)d_in[6];
    const float* lin2_w    = (const float*)d_in[7];
    const float* lin2_b    = (const float*)d_in[8];
    const float* n1_g = (const float*)d_in[9];
    const float* n1_b = (const float*)d_in[10];
    const float* n2_g = (const float*)d_in[11];
    const float* n2_b = (const float*)d_in[12];

    char* ws = (char*)d_ws;
    size_t off = 0;
    auto alloc = [&](size_t bytes) { char* p = ws + off; off += (bytes + 255) & ~(size_t)255; return p; };

    __bf16* src_bf = (__bf16*)alloc((size_t)M_ * D_ * 2);      // -> attn_o after QKV GEMM
    __bf16* w1     = (__bf16*)alloc((size_t)QKV_N * D_ * 2);
    __bf16* w2     = (__bf16*)alloc((size_t)D_ * D_ * 2);
    __bf16* w3     = (__bf16*)alloc((size_t)DFF_ * D_ * 2);
    __bf16* w4     = (__bf16*)alloc((size_t)D_ * DFF_ * 2);
    __bf16* qkv    = (__bf16*)alloc((size_t)M_ * QKV_N * 2);   // 48MB
    char*   h_r    = alloc((size_t)M_ * DFF_ * 2);             // 64MB: o0,o1 then hbf
    __bf16* xbf    = (__bf16*)alloc((size_t)M_ * D_ * 2);      // x bf16; -> f1 after lin1
    float*  xf     = (float*)alloc((size_t)M_ * D_ * 4);
    __bf16* vt     = (__bf16*)alloc((size_t)B_ * H_ * HD_ * S_ * 2); // 16MB; -> f0 after attn

    const size_t PART = (size_t)M_ * D_;   // 8M elems = 16MB bf16
    __bf16* attn_o = src_bf;               // src_bf dead after QKV GEMM
    __bf16* o0 = (__bf16*)h_r;             // outproj split-K partials (die at LN1)
    __bf16* o1 = o0 + PART;
    __bf16* hbf = (__bf16*)h_r;            // lin1 out (after LN1)
    __bf16* f0 = vt;                       // lin2 partials
    __bf16* f1 = xbf;                      // xbf dead after lin1

    const size_t SHM = 3 * 2 * 8192 * sizeof(__bf16);   // 96 KB ring LDS

    // 1) all fp32->bf16 conversions
    cvt_all<<<(CB4 + 255) / 256, 256, 0, stream>>>(
        src, in_proj_w, out_w, lin1_w, lin2_w, src_bf, w1, w2, w3, w4);

    // 2) QKV projection: qkv = src*W1^T + b   [8192,3072] bf16
    gemm256<true, false, true, false><<<dim3(M_ / 256, QKV_N / 256), 512, SHM, stream>>>(
        src_bf, w1, in_proj_b, qkv, nullptr, QKV_N, D_, D_);

    // 3) V transpose -> vt[bh][d][t]
    v_transpose<<<dim3(S_ / 64, B_ * H_), 256, 0, stream>>>(qkv, vt);

    // 4) attention -> attn_o bf16
    attn_flash<<<dim3(S_ / 64, B_ * H_), 256, 0, stream>>>(qkv, vt, attn_o);

    // 5) out projection, split-K x2 (Kloop=512): o0/o1 bf16 partials
    gemm256<true, false, false, true><<<dim3(M_ / 256, D_ / 256, 2), 512, SHM, stream>>>(
        attn_o, w2, nullptr, o0, o1, D_, D_ / 2, D_);

    // 6) x = LN(src + o0 + o1 + out_b) -> xf fp32, xbf bf16
    ln_res3<<<M_, 256, 0, stream>>>(src, o0, o1, out_b, n1_g, n1_b, xf, xbf);

    // 7) h = relu(x*W3^T + b3)  bf16 [8192,4096]
    gemm256<true, true, true, false><<<dim3(M_ / 256, DFF_ / 256), 512, SHM, stream>>>(
        xbf, w3, lin1_b, hbf, nullptr, DFF_, D_, D_);

    // 8) lin2, split-K x2 (Kloop=2048): f0/f1 bf16 partials
    gemm256<true, false, false, true><<<dim3(M_ / 256, D_ / 256, 2), 512, SHM, stream>>>(
        hbf, w4, nullptr, f0, f1, D_, DFF_ / 2, DFF_);

    // 9) out = LN(xf + f0 + f1 + lin2_b)  fp32
    ln_res3<<<M_, 256, 0, stream>>>(xf, f0, f1, lin2_b, n2_g, n2_b, (float*)d_out, nullptr);
}

// Round 4
// 489.770 us; speedup vs baseline: 1.1278x; 1.1278x over previous
//
#include <hip/hip_runtime.h>
#include <cstdint>
#include <cstddef>

// ---- sizes (compile-time for this problem) ----
#define S_  1024
#define B_  8
#define D_  1024
#define H_  16
#define HD_ 64
#define DFF_ 4096
#define M_  (S_*B_)      // 8192 rows
#define QKV_N (3*D_)     // 3072

typedef float f32x4 __attribute__((ext_vector_type(4)));
typedef __bf16 bf16x8 __attribute__((ext_vector_type(8)));
typedef __bf16 bf16x4 __attribute__((ext_vector_type(4)));

#define GLDS16(gp, lp) __builtin_amdgcn_global_load_lds( \
    (__attribute__((address_space(1))) void*)(gp), \
    (__attribute__((address_space(3))) void*)(lp), 16, 0, 0)

// ---------------------------------------------------------------------------
// fused fp32 -> bf16 conversion of all 5 tensors in one launch
// ---------------------------------------------------------------------------
#define CB0 (M_*D_/4)
#define CB1 (CB0 + QKV_N*D_/4)
#define CB2 (CB1 + D_*D_/4)
#define CB3 (CB2 + DFF_*D_/4)
#define CB4 (CB3 + D_*DFF_/4)

__global__ __launch_bounds__(256)
void cvt_all(const float* __restrict__ src, const float* __restrict__ w1f,
             const float* __restrict__ w2f, const float* __restrict__ w3f,
             const float* __restrict__ w4f,
             __bf16* __restrict__ src_bf, __bf16* __restrict__ w1,
             __bf16* __restrict__ w2, __bf16* __restrict__ w3,
             __bf16* __restrict__ w4)
{
    int i = blockIdx.x * 256 + threadIdx.x;
    const float* in; __bf16* out; int off;
    if      (i < CB0) { in = src; out = src_bf; off = 0;   }
    else if (i < CB1) { in = w1f; out = w1;     off = CB0; }
    else if (i < CB2) { in = w2f; out = w2;     off = CB1; }
    else if (i < CB3) { in = w3f; out = w3;     off = CB2; }
    else if (i < CB4) { in = w4f; out = w4;     off = CB3; }
    else return;
    int j = i - off;
    float4 v = *(const float4*)(in + (size_t)j * 4);
    __bf16 t[4] = {(__bf16)v.x, (__bf16)v.y, (__bf16)v.z, (__bf16)v.w};
    *(uint2*)(out + (size_t)j * 4) = *(uint2*)t;
}

// ---------------------------------------------------------------------------
// GEMM: C = A[M,K]*W[N,K]^T (+bias). 256x256 tile, BK=32, 8 waves (2x4),
// 3-deep LDS ring pipeline (96KB dynamic LDS), counted vmcnt, raw s_barrier.
// Chunked XCD raster + source-side LDS swizzle + j-inner C store (round 2).
// ---------------------------------------------------------------------------
template<bool OUT_BF16, bool RELU, bool ADD_BIAS, bool SPLITZ>
__global__ __launch_bounds__(512, 2)
void gemm256(const __bf16* __restrict__ A, const __bf16* __restrict__ W,
             const float* __restrict__ bias,
             void* __restrict__ Cv0, void* __restrict__ Cv1,
             int N, int Kloop, int lda)
{
    extern __shared__ __bf16 lds[];
    __bf16* As = lds;                 // 3 x [256][32] bf16 = 48KB
    __bf16* Bs = lds + 3 * 8192;      // 3 x [256][32] bf16 = 48KB

    const int tid  = threadIdx.x;
    const int lane = tid & 63;
    const int wv   = tid >> 6;          // 0..7
    const int quad = lane >> 4;
    const int l15  = lane & 15;
    const int wm   = (wv >> 2) * 128;   // 0 / 128
    const int wn   = (wv & 3) * 64;     // 0 / 64 / 128 / 192

    // chunked raster + XCD-contiguous assignment (all grids: nwg%32==0, GM%8==0)
    const int id  = blockIdx.y * gridDim.x + blockIdx.x;
    const int nwg = gridDim.x * gridDim.y;
    const int q8  = nwg >> 3;
    const int k   = (id & 7) * q8 + (id >> 3);   // XCD id&7 gets contiguous k
    const int within = k & 31;                    // 0..31 inside chunk
    const int chunk  = k >> 5;
    const int nchm   = gridDim.x >> 3;            // chunk columns (GM/8)
    const int cm     = chunk % nchm;
    const int cn     = chunk / nchm;
    const int m0 = (cm * 8 + (within & 7)) * 256;
    const int n0 = (cn * 4 + (within >> 3)) * 256;

    void* Cv = Cv0;
    if (SPLITZ) {
        const int koff = blockIdx.z * Kloop;
        A += koff;
        W += koff;
        if (blockIdx.z) Cv = Cv1;
    }

    const int nt = Kloop >> 5;          // K-tiles of 32

    // stage one K-tile (A: 256x32, B: 256x32) -> 4 x GLDS16 per thread.
    // LDS dest is linear; the k-slot is pre-swizzled on the global source.
    #define STAGE(kt, buf) do { \
        const int k0s = (kt) << 5; \
        _Pragma("unroll") \
        for (int u = 0; u < 2; ++u) { \
            int c   = u * 512 + tid; \
            int row = c >> 2; \
            int ssl = (c & 3) ^ ((row >> 1) & 3); \
            GLDS16(A + (size_t)(m0 + row) * lda + k0s + ssl * 8, \
                   (char*)(As + (buf) * 8192) + c * 16); \
            GLDS16(W + (size_t)(n0 + row) * lda + k0s + ssl * 8, \
                   (char*)(Bs + (buf) * 8192) + c * 16); \
        } \
    } while (0)

    // prologue: fill 2 pipeline stages
    STAGE(0, 0);
    STAGE(1, 1);
    asm volatile("s_waitcnt vmcnt(4)" ::: "memory");
    __builtin_amdgcn_s_barrier();
    __builtin_amdgcn_sched_barrier(0);

    f32x4 acc[8][4] = {};

    int cur = 0, stg = 2;
    for (int t = 0; t < nt; ++t) {
        if (t + 2 < nt) STAGE(t + 2, stg);

        bf16x8 bf[4], af[8];
        #pragma unroll
        for (int j = 0; j < 4; ++j) {
            int rb = wn + j * 16 + l15;
            bf[j] = *(const bf16x8*)(Bs + cur * 8192 + rb * 32 + (quad ^ ((rb >> 1) & 3)) * 8);
        }
        #pragma unroll
        for (int i = 0; i < 8; ++i) {
            int ra = wm + i * 16 + l15;
            af[i] = *(const bf16x8*)(As + cur * 8192 + ra * 32 + (quad ^ ((ra >> 1) & 3)) * 8);
        }

        __builtin_amdgcn_s_setprio(1);
        #pragma unroll
        for (int i = 0; i < 8; ++i)
            #pragma unroll
            for (int j = 0; j < 4; ++j)
                acc[i][j] = __builtin_amdgcn_mfma_f32_16x16x32_bf16(af[i], bf[j], acc[i][j], 0, 0, 0);
        __builtin_amdgcn_s_setprio(0);

        if (t + 1 < nt) {
            if (t + 2 < nt) { asm volatile("s_waitcnt vmcnt(4)" ::: "memory"); }
            else            { asm volatile("s_waitcnt vmcnt(0)" ::: "memory"); }
            __builtin_amdgcn_s_barrier();
            __builtin_amdgcn_sched_barrier(0);
        }
        if (++cur == 3) cur = 0;
        if (++stg == 3) stg = 0;
    }
    #undef STAGE

    // epilogue: row = m0+wm+i*16+quad*4+r ; col = n0+wn+j*16+l15.
    // j innermost: 4 back-to-back 32B stores complete each 128B line.
    float bvj[4];
    #pragma unroll
    for (int j = 0; j < 4; ++j)
        bvj[j] = ADD_BIAS ? bias[n0 + wn + j * 16 + l15] : 0.f;
    #pragma unroll
    for (int i = 0; i < 8; ++i) {
        const int rbase = m0 + wm + i * 16 + quad * 4;
        #pragma unroll
        for (int r = 0; r < 4; ++r) {
            #pragma unroll
            for (int j = 0; j < 4; ++j) {
                const int col = n0 + wn + j * 16 + l15;
                float v = acc[i][j][r] + bvj[j];
                if (RELU) v = fmaxf(v, 0.f);
                if (OUT_BF16)
                    ((__bf16*)Cv)[(size_t)(rbase + r) * N + col] = (__bf16)v;
                else
                    ((float*)Cv)[(size_t)(rbase + r) * N + col] = v;
            }
        }
    }
}

// ---------------------------------------------------------------------------
// V transpose: qkv V-part -> vt[bh][d][t]
// ---------------------------------------------------------------------------
__global__ __launch_bounds__(256)
void v_transpose(const __bf16* __restrict__ qkv, __bf16* __restrict__ vt)
{
    __shared__ __bf16 T[64 * 65];
    const int tid = threadIdx.x;
    const int t0  = blockIdx.x * 64;
    const int bh  = blockIdx.y;
    const int b   = bh & (B_ - 1);
    const int h   = bh / B_;

    #pragma unroll
    for (int j = 0; j < 2; ++j) {
        int c = j * 256 + tid;
        int i = c >> 3, cc = c & 7;
        const __bf16* g = qkv + (size_t)((t0 + i) * B_ + b) * QKV_N + 2 * D_ + h * HD_ + cc * 8;
        bf16x8 v = *(const bf16x8*)g;
        #pragma unroll
        for (int u = 0; u < 8; ++u) T[(cc * 8 + u) * 65 + i] = v[u];
    }
    __syncthreads();
    #pragma unroll
    for (int j = 0; j < 2; ++j) {
        int c = j * 256 + tid;
        int d = c >> 3, cc = c & 7;
        __bf16 pk[8];
        #pragma unroll
        for (int u = 0; u < 8; ++u) pk[u] = T[d * 65 + cc * 8 + u];
        *(uint4*)(vt + ((size_t)bh * HD_ + d) * S_ + t0 + cc * 8) = *(uint4*)pk;
    }
}

// ---------------------------------------------------------------------------
// Flash attention, S^T formulation.
// Round-4: keep r3's verified XOR swizzle (2-way max on all LDS traffic) but
// stage Q/K/V via global_load_lds with pre-swizzled GLOBAL source + linear
// LDS dest (no VGPR round-trip -> no scratch spills, the r3 regression).
// K/V double-buffered: tile t+1's GLDS16 issued before tile t's compute,
// one __syncthreads() per tile (its implicit vmcnt(0) is the completion
// wait; loads fly across the whole QK+softmax+PV phase).
// ---------------------------------------------------------------------------
#define AST 64

__global__ __launch_bounds__(256)
void attn_flash(const __bf16* __restrict__ qkv, const __bf16* __restrict__ vt,
                __bf16* __restrict__ out)
{
    __shared__ __bf16 Qs[64 * AST];
    __shared__ __bf16 Ps[64 * AST];
    __shared__ __bf16 Ks[2][64 * AST];
    __shared__ __bf16 Vs[2][64 * AST];

    const int tid  = threadIdx.x;
    const int lane = tid & 63;
    const int wv   = tid >> 6;
    const int quad = lane >> 4;
    const int l15  = lane & 15;

    // grid = (16, 128): give each XCD 256 contiguous k -> 16 whole heads per
    // XCD, K/V stays L2-resident.
    const int id = blockIdx.y * gridDim.x + blockIdx.x;
    const int k  = (id & 7) * ((S_ / 64) * B_ * H_ / 8) + (id >> 3);
    const int s0 = (k & 15) * 64;
    const int bh = k >> 4;
    const int b  = bh & (B_ - 1);
    const int h  = bh / B_;

    // stage Q + K/V tile 0 via GLDS16. LDS dest linear (c*16); global source
    // slot pre-swizzled: row i, slot cc -> global slot cc^(i&7).
    #pragma unroll
    for (int j = 0; j < 2; ++j) {
        int c = j * 256 + tid;
        int i = c >> 3, cc = c & 7;
        int scc = cc ^ (i & 7);
        GLDS16(qkv + (size_t)((s0 + i) * B_ + b) * QKV_N + h * HD_ + scc * 8,
               (char*)Qs + c * 16);
        GLDS16(qkv + (size_t)(i * B_ + b) * QKV_N + D_ + h * HD_ + scc * 8,
               (char*)(Ks[0]) + c * 16);
        GLDS16(vt + ((size_t)bh * HD_ + i) * S_ + scc * 8,
               (char*)(Vs[0]) + c * 16);
    }
    __syncthreads();   // implicit vmcnt(0): Q, K0, V0 landed

    f32x4 oacc[4] = {};
    float m_run = -1e30f, l_run = 0.f;
    const float C2    = 0.125f * 1.44269504f;
    const float LOG2E = 1.44269504f;
    const int qrow = wv * 16 + l15;

    const int nt = S_ / 64;
    for (int it = 0; it < nt; ++it) {
        const int cur = it & 1;

        // issue next tile's K/V loads; they fly across this tile's compute.
        // buf cur^1 was last read at iter it-1; barrier at end of it-1
        // guarantees those reads completed.
        if (it + 1 < nt) {
            const int t1 = (it + 1) * 64;
            #pragma unroll
            for (int j = 0; j < 2; ++j) {
                int c = j * 256 + tid;
                int i = c >> 3, cc = c & 7;
                int scc = cc ^ (i & 7);
                GLDS16(qkv + (size_t)((t1 + i) * B_ + b) * QKV_N + D_ + h * HD_ + scc * 8,
                       (char*)(Ks[cur ^ 1]) + c * 16);
                GLDS16(vt + ((size_t)bh * HD_ + i) * S_ + t1 + scc * 8,
                       (char*)(Vs[cur ^ 1]) + c * 16);
            }
        }

        // QK^T (S^T: lane holds 16 k's for q = qrow)
        f32x4 sacc[4] = {};
        #pragma unroll
        for (int kk = 0; kk < 2; ++kk) {
            bf16x8 bq = *(const bf16x8*)(Qs + qrow * AST + (((kk * 4 + quad) ^ (qrow & 7)) * 8));
            #pragma unroll
            for (int j = 0; j < 4; ++j) {
                int krow = j * 16 + l15;
                bf16x8 ak = *(const bf16x8*)(&Ks[cur][krow * AST + (((kk * 4 + quad) ^ (krow & 7)) * 8)]);
                sacc[j] = __builtin_amdgcn_mfma_f32_16x16x32_bf16(ak, bq, sacc[j], 0, 0, 0);
            }
        }

        float mx = sacc[0][0];
        #pragma unroll
        for (int j = 0; j < 4; ++j)
            #pragma unroll
            for (int r = 0; r < 4; ++r) mx = fmaxf(mx, sacc[j][r]);
        mx = fmaxf(mx, __shfl_xor(mx, 16, 64));
        mx = fmaxf(mx, __shfl_xor(mx, 32, 64));
        float mnew = fmaxf(m_run, mx * 0.125f);
        float k1 = mnew * LOG2E;
        float rs = 0.f;
        #pragma unroll
        for (int j = 0; j < 4; ++j)
            #pragma unroll
            for (int r = 0; r < 4; ++r) {
                float p = __builtin_amdgcn_exp2f(sacc[j][r] * C2 - k1);
                sacc[j][r] = p;
                rs += p;
            }
        rs += __shfl_xor(rs, 16, 64);
        rs += __shfl_xor(rs, 32, 64);
        float alpha = __builtin_amdgcn_exp2f((m_run - mnew) * LOG2E);
        l_run = l_run * alpha + rs;
        m_run = mnew;

        // P write (swizzled, verified r3): col block j -> 16B slot
        // (j*2+(quad>>1))^(qrow&7), 8B half quad&1. Rows are wave-private.
        #pragma unroll
        for (int j = 0; j < 4; ++j) {
            __bf16 pk[4] = {(__bf16)sacc[j][0], (__bf16)sacc[j][1],
                            (__bf16)sacc[j][2], (__bf16)sacc[j][3]};
            int s16 = (j * 2 + (quad >> 1)) ^ (qrow & 7);
            *(uint2*)(Ps + qrow * AST + s16 * 8 + (quad & 1) * 4) = *(uint2*)pk;
        }

        #pragma unroll
        for (int r = 0; r < 4; ++r) {
            float ar = __shfl(alpha, quad * 4 + r, 64);
            #pragma unroll
            for (int jd = 0; jd < 4; ++jd) oacc[jd][r] *= ar;
        }

        // PV
        #pragma unroll
        for (int kk = 0; kk < 2; ++kk) {
            bf16x8 ap = *(const bf16x8*)(Ps + qrow * AST + (((kk * 4 + quad) ^ (qrow & 7)) * 8));
            #pragma unroll
            for (int jd = 0; jd < 4; ++jd) {
                int vrow = jd * 16 + l15;
                bf16x8 bv = *(const bf16x8*)(&Vs[cur][vrow * AST + (((kk * 4 + quad) ^ (vrow & 7)) * 8)]);
                oacc[jd] = __builtin_amdgcn_mfma_f32_16x16x32_bf16(ap, bv, oacc[jd], 0, 0, 0);
            }
        }

        // single barrier per tile: drains vmcnt (next K/V landed) and orders
        // this tile's LDS reads before iter it+1 overwrites buf cur.
        __syncthreads();
    }

    float linv = 1.f / l_run;
    #pragma unroll
    for (int r = 0; r < 4; ++r) {
        float lr = __shfl(linv, quad * 4 + r, 64);
        int s = s0 + wv * 16 + quad * 4 + r;
        #pragma unroll
        for (int jd = 0; jd < 4; ++jd) {
            int d = jd * 16 + l15;
            out[(size_t)(s * B_ + b) * D_ + h * HD_ + d] = (__bf16)(oacc[jd][r] * lr);
        }
    }
}

// ---------------------------------------------------------------------------
// LayerNorm( xa + p0 + p1 + bias[col] ) * g + beta -> yout fp32 (+ ybf bf16)
// ---------------------------------------------------------------------------
__global__ __launch_bounds__(256)
void ln_res3(const float* __restrict__ xa, const __bf16* __restrict__ p0,
             const __bf16* __restrict__ p1, const float* __restrict__ bias,
             const float* __restrict__ g, const float* __restrict__ beta,
             float* __restrict__ yout, __bf16* __restrict__ ybf)
{
    __shared__ float red[8];
    const int row = blockIdx.x;
    const int tid = threadIdx.x;
    const size_t base = (size_t)row * D_ + tid * 4;

    float4 a  = *(const float4*)(xa + base);
    bf16x4 q0 = *(const bf16x4*)(p0 + base);
    bf16x4 q1 = *(const bf16x4*)(p1 + base);
    float4 bb = *(const float4*)(bias + tid * 4);
    float x0 = a.x + (float)q0[0] + (float)q1[0] + bb.x;
    float x1 = a.y + (float)q0[1] + (float)q1[1] + bb.y;
    float x2 = a.z + (float)q0[2] + (float)q1[2] + bb.z;
    float x3 = a.w + (float)q0[3] + (float)q1[3] + bb.w;

    float s  = x0 + x1 + x2 + x3;
    float ss = x0 * x0 + x1 * x1 + x2 * x2 + x3 * x3;
    for (int msk = 1; msk <= 32; msk <<= 1) {
        s  += __shfl_xor(s,  msk, 64);
        ss += __shfl_xor(ss, msk, 64);
    }
    const int wv = tid >> 6;
    if ((tid & 63) == 0) { red[wv] = s; red[4 + wv] = ss; }
    __syncthreads();
    s  = red[0] + red[1] + red[2] + red[3];
    ss = red[4] + red[5] + red[6] + red[7];
    float mean = s * (1.f / D_);
    float var  = ss * (1.f / D_) - mean * mean;
    float rstd = rsqrtf(var + 1e-5f);

    float4 gv = *(const float4*)(g + tid * 4);
    float4 bv = *(const float4*)(beta + tid * 4);
    float y0 = (x0 - mean) * rstd * gv.x + bv.x;
    float y1 = (x1 - mean) * rstd * gv.y + bv.y;
    float y2 = (x2 - mean) * rstd * gv.z + bv.z;
    float y3 = (x3 - mean) * rstd * gv.w + bv.w;
    *(float4*)(yout + base) = make_float4(y0, y1, y2, y3);
    if (ybf) {
        __bf16 t[4] = {(__bf16)y0, (__bf16)y1, (__bf16)y2, (__bf16)y3};
        *(uint2*)(ybf + base) = *(uint2*)t;
    }
}

// ---------------------------------------------------------------------------
extern "C" void kernel_launch(void* const* d_in, const int* in_sizes, int n_in,
                              void* d_out, int out_size, void* d_ws, size_t ws_size,
                              hipStream_t stream)
{
    const float* src       = (const float*)d_in[0];
    const float* in_proj_w = (const float*)d_in[1];
    const float* in_proj_b = (const float*)d_in[2];
    const float* out_w     = (const float*)d_in[3];
    const float* out_b     = (const float*)d_in[4];
    const float* lin1_w    = (const float*)d_in[5];
    const float* lin1_b    = (const float*)d_in[6];
    const float* lin2_w    = (const float*)d_in[7];
    const float* lin2_b    = (const float*)d_in[8];
    const float* n1_g = (const float*)d_in[9];
    const float* n1_b = (const float*)d_in[10];
    const float* n2_g = (const float*)d_in[11];
    const float* n2_b = (const float*)d_in[12];

    char* ws = (char*)d_ws;
    size_t off = 0;
    auto alloc = [&](size_t bytes) { char* p = ws + off; off += (bytes + 255) & ~(size_t)255; return p; };

    __bf16* src_bf = (__bf16*)alloc((size_t)M_ * D_ * 2);      // -> attn_o after QKV GEMM
    __bf16* w1     = (__bf16*)alloc((size_t)QKV_N * D_ * 2);
    __bf16* w2     = (__bf16*)alloc((size_t)D_ * D_ * 2);
    __bf16* w3     = (__bf16*)alloc((size_t)DFF_ * D_ * 2);
    __bf16* w4     = (__bf16*)alloc((size_t)D_ * DFF_ * 2);
    __bf16* qkv    = (__bf16*)alloc((size_t)M_ * QKV_N * 2);   // 48MB
    char*   h_r    = alloc((size_t)M_ * DFF_ * 2);             // 64MB: o0,o1 then hbf
    __bf16* xbf    = (__bf16*)alloc((size_t)M_ * D_ * 2);      // x bf16; -> f1 after lin1
    float*  xf     = (float*)alloc((size_t)M_ * D_ * 4);
    __bf16* vt     = (__bf16*)alloc((size_t)B_ * H_ * HD_ * S_ * 2); // 16MB; -> f0 after attn

    const size_t PART = (size_t)M_ * D_;   // 8M elems = 16MB bf16
    __bf16* attn_o = src_bf;               // src_bf dead after QKV GEMM
    __bf16* o0 = (__bf16*)h_r;             // outproj split-K partials (die at LN1)
    __bf16* o1 = o0 + PART;
    __bf16* hbf = (__bf16*)h_r;            // lin1 out (after LN1)
    __bf16* f0 = vt;                       // lin2 partials
    __bf16* f1 = xbf;                      // xbf dead after lin1

    const size_t SHM = 3 * 2 * 8192 * sizeof(__bf16);   // 96 KB ring LDS

    // 1) all fp32->bf16 conversions
    cvt_all<<<(CB4 + 255) / 256, 256, 0, stream>>>(
        src, in_proj_w, out_w, lin1_w, lin2_w, src_bf, w1, w2, w3, w4);

    // 2) QKV projection: qkv = src*W1^T + b   [8192,3072] bf16
    gemm256<true, false, true, false><<<dim3(M_ / 256, QKV_N / 256), 512, SHM, stream>>>(
        src_bf, w1, in_proj_b, qkv, nullptr, QKV_N, D_, D_);

    // 3) V transpose -> vt[bh][d][t]
    v_transpose<<<dim3(S_ / 64, B_ * H_), 256, 0, stream>>>(qkv, vt);

    // 4) attention -> attn_o bf16
    attn_flash<<<dim3(S_ / 64, B_ * H_), 256, 0, stream>>>(qkv, vt, attn_o);

    // 5) out projection, split-K x2 (Kloop=512): o0/o1 bf16 partials
    gemm256<true, false, false, true><<<dim3(M_ / 256, D_ / 256, 2), 512, SHM, stream>>>(
        attn_o, w2, nullptr, o0, o1, D_, D_ / 2, D_);

    // 6) x = LN(src + o0 + o1 + out_b) -> xf fp32, xbf bf16
    ln_res3<<<M_, 256, 0, stream>>>(src, o0, o1, out_b, n1_g, n1_b, xf, xbf);

    // 7) h = relu(x*W3^T + b3)  bf16 [8192,4096]
    gemm256<true, true, true, false><<<dim3(M_ / 256, DFF_ / 256), 512, SHM, stream>>>(
        xbf, w3, lin1_b, hbf, nullptr, DFF_, D_, D_);

    // 8) lin2, split-K x2 (Kloop=2048): f0/f1 bf16 partials
    gemm256<true, false, false, true><<<dim3(M_ / 256, D_ / 256, 2), 512, SHM, stream>>>(
        hbf, w4, nullptr, f0, f1, D_, DFF_ / 2, DFF_);

    // 9) out = LN(xf + f0 + f1 + lin2_b)  fp32
    ln_res3<<<M_, 256, 0, stream>>>(xf, f0, f1, lin2_b, n2_g, n2_b, (float*)d_out, nullptr);
}

// Round 5
// 465.449 us; speedup vs baseline: 1.1867x; 1.0523x over previous
//
#include <hip/hip_runtime.h>
#include <cstdint>
#include <cstddef>

// ---- sizes (compile-time for this problem) ----
#define S_  1024
#define B_  8
#define D_  1024
#define H_  16
#define HD_ 64
#define DFF_ 4096
#define M_  (S_*B_)      // 8192 rows
#define QKV_N (3*D_)     // 3072

typedef float f32x4 __attribute__((ext_vector_type(4)));
typedef __bf16 bf16x8 __attribute__((ext_vector_type(8)));
typedef __bf16 bf16x4 __attribute__((ext_vector_type(4)));

#define GLDS16(gp, lp) __builtin_amdgcn_global_load_lds( \
    (__attribute__((address_space(1))) void*)(gp), \
    (__attribute__((address_space(3))) void*)(lp), 16, 0, 0)

// ---------------------------------------------------------------------------
// fused fp32 -> bf16 conversion of all 5 tensors in one launch
// ---------------------------------------------------------------------------
#define CB0 (M_*D_/4)
#define CB1 (CB0 + QKV_N*D_/4)
#define CB2 (CB1 + D_*D_/4)
#define CB3 (CB2 + DFF_*D_/4)
#define CB4 (CB3 + D_*DFF_/4)

__global__ __launch_bounds__(256)
void cvt_all(const float* __restrict__ src, const float* __restrict__ w1f,
             const float* __restrict__ w2f, const float* __restrict__ w3f,
             const float* __restrict__ w4f,
             __bf16* __restrict__ src_bf, __bf16* __restrict__ w1,
             __bf16* __restrict__ w2, __bf16* __restrict__ w3,
             __bf16* __restrict__ w4)
{
    int i = blockIdx.x * 256 + threadIdx.x;
    const float* in; __bf16* out; int off;
    if      (i < CB0) { in = src; out = src_bf; off = 0;   }
    else if (i < CB1) { in = w1f; out = w1;     off = CB0; }
    else if (i < CB2) { in = w2f; out = w2;     off = CB1; }
    else if (i < CB3) { in = w3f; out = w3;     off = CB2; }
    else if (i < CB4) { in = w4f; out = w4;     off = CB3; }
    else return;
    int j = i - off;
    float4 v = *(const float4*)(in + (size_t)j * 4);
    __bf16 t[4] = {(__bf16)v.x, (__bf16)v.y, (__bf16)v.z, (__bf16)v.w};
    *(uint2*)(out + (size_t)j * 4) = *(uint2*)t;
}

// ---------------------------------------------------------------------------
// GEMM: C = A[M,K]*W[N,K]^T (+bias). 256x256 tile, BK=32, 8 waves (2x4),
// 3-deep LDS ring pipeline (96KB dynamic LDS), counted vmcnt, raw s_barrier.
// Chunked XCD raster + source-side LDS swizzle + j-inner C store (round 2).
// ---------------------------------------------------------------------------
template<bool OUT_BF16, bool RELU, bool ADD_BIAS, bool SPLITZ>
__global__ __launch_bounds__(512, 2)
void gemm256(const __bf16* __restrict__ A, const __bf16* __restrict__ W,
             const float* __restrict__ bias,
             void* __restrict__ Cv0, void* __restrict__ Cv1,
             int N, int Kloop, int lda)
{
    extern __shared__ __bf16 lds[];
    __bf16* As = lds;                 // 3 x [256][32] bf16 = 48KB
    __bf16* Bs = lds + 3 * 8192;      // 3 x [256][32] bf16 = 48KB

    const int tid  = threadIdx.x;
    const int lane = tid & 63;
    const int wv   = tid >> 6;          // 0..7
    const int quad = lane >> 4;
    const int l15  = lane & 15;
    const int wm   = (wv >> 2) * 128;   // 0 / 128
    const int wn   = (wv & 3) * 64;     // 0 / 64 / 128 / 192

    // chunked raster + XCD-contiguous assignment (all grids: nwg%32==0, GM%8==0)
    const int id  = blockIdx.y * gridDim.x + blockIdx.x;
    const int nwg = gridDim.x * gridDim.y;
    const int q8  = nwg >> 3;
    const int k   = (id & 7) * q8 + (id >> 3);   // XCD id&7 gets contiguous k
    const int within = k & 31;                    // 0..31 inside chunk
    const int chunk  = k >> 5;
    const int nchm   = gridDim.x >> 3;            // chunk columns (GM/8)
    const int cm     = chunk % nchm;
    const int cn     = chunk / nchm;
    const int m0 = (cm * 8 + (within & 7)) * 256;
    const int n0 = (cn * 4 + (within >> 3)) * 256;

    void* Cv = Cv0;
    if (SPLITZ) {
        const int koff = blockIdx.z * Kloop;
        A += koff;
        W += koff;
        if (blockIdx.z) Cv = Cv1;
    }

    const int nt = Kloop >> 5;          // K-tiles of 32

    // stage one K-tile (A: 256x32, B: 256x32) -> 4 x GLDS16 per thread.
    // LDS dest is linear; the k-slot is pre-swizzled on the global source.
    #define STAGE(kt, buf) do { \
        const int k0s = (kt) << 5; \
        _Pragma("unroll") \
        for (int u = 0; u < 2; ++u) { \
            int c   = u * 512 + tid; \
            int row = c >> 2; \
            int ssl = (c & 3) ^ ((row >> 1) & 3); \
            GLDS16(A + (size_t)(m0 + row) * lda + k0s + ssl * 8, \
                   (char*)(As + (buf) * 8192) + c * 16); \
            GLDS16(W + (size_t)(n0 + row) * lda + k0s + ssl * 8, \
                   (char*)(Bs + (buf) * 8192) + c * 16); \
        } \
    } while (0)

    // prologue: fill 2 pipeline stages
    STAGE(0, 0);
    STAGE(1, 1);
    asm volatile("s_waitcnt vmcnt(4)" ::: "memory");
    __builtin_amdgcn_s_barrier();
    __builtin_amdgcn_sched_barrier(0);

    f32x4 acc[8][4] = {};

    int cur = 0, stg = 2;
    for (int t = 0; t < nt; ++t) {
        if (t + 2 < nt) STAGE(t + 2, stg);

        bf16x8 bf[4], af[8];
        #pragma unroll
        for (int j = 0; j < 4; ++j) {
            int rb = wn + j * 16 + l15;
            bf[j] = *(const bf16x8*)(Bs + cur * 8192 + rb * 32 + (quad ^ ((rb >> 1) & 3)) * 8);
        }
        #pragma unroll
        for (int i = 0; i < 8; ++i) {
            int ra = wm + i * 16 + l15;
            af[i] = *(const bf16x8*)(As + cur * 8192 + ra * 32 + (quad ^ ((ra >> 1) & 3)) * 8);
        }

        __builtin_amdgcn_s_setprio(1);
        #pragma unroll
        for (int i = 0; i < 8; ++i)
            #pragma unroll
            for (int j = 0; j < 4; ++j)
                acc[i][j] = __builtin_amdgcn_mfma_f32_16x16x32_bf16(af[i], bf[j], acc[i][j], 0, 0, 0);
        __builtin_amdgcn_s_setprio(0);

        if (t + 1 < nt) {
            if (t + 2 < nt) { asm volatile("s_waitcnt vmcnt(4)" ::: "memory"); }
            else            { asm volatile("s_waitcnt vmcnt(0)" ::: "memory"); }
            __builtin_amdgcn_s_barrier();
            __builtin_amdgcn_sched_barrier(0);
        }
        if (++cur == 3) cur = 0;
        if (++stg == 3) stg = 0;
    }
    #undef STAGE

    // epilogue: row = m0+wm+i*16+quad*4+r ; col = n0+wn+j*16+l15.
    // j innermost: 4 back-to-back 32B stores complete each 128B line.
    float bvj[4];
    #pragma unroll
    for (int j = 0; j < 4; ++j)
        bvj[j] = ADD_BIAS ? bias[n0 + wn + j * 16 + l15] : 0.f;
    #pragma unroll
    for (int i = 0; i < 8; ++i) {
        const int rbase = m0 + wm + i * 16 + quad * 4;
        #pragma unroll
        for (int r = 0; r < 4; ++r) {
            #pragma unroll
            for (int j = 0; j < 4; ++j) {
                const int col = n0 + wn + j * 16 + l15;
                float v = acc[i][j][r] + bvj[j];
                if (RELU) v = fmaxf(v, 0.f);
                if (OUT_BF16)
                    ((__bf16*)Cv)[(size_t)(rbase + r) * N + col] = (__bf16)v;
                else
                    ((float*)Cv)[(size_t)(rbase + r) * N + col] = v;
            }
        }
    }
}

// ---------------------------------------------------------------------------
// V transpose: qkv V-part -> vt[bh][d][t]
// ---------------------------------------------------------------------------
__global__ __launch_bounds__(256)
void v_transpose(const __bf16* __restrict__ qkv, __bf16* __restrict__ vt)
{
    __shared__ __bf16 T[64 * 65];
    const int tid = threadIdx.x;
    const int t0  = blockIdx.x * 64;
    const int bh  = blockIdx.y;
    const int b   = bh & (B_ - 1);
    const int h   = bh / B_;

    #pragma unroll
    for (int j = 0; j < 2; ++j) {
        int c = j * 256 + tid;
        int i = c >> 3, cc = c & 7;
        const __bf16* g = qkv + (size_t)((t0 + i) * B_ + b) * QKV_N + 2 * D_ + h * HD_ + cc * 8;
        bf16x8 v = *(const bf16x8*)g;
        #pragma unroll
        for (int u = 0; u < 8; ++u) T[(cc * 8 + u) * 65 + i] = v[u];
    }
    __syncthreads();
    #pragma unroll
    for (int j = 0; j < 2; ++j) {
        int c = j * 256 + tid;
        int d = c >> 3, cc = c & 7;
        __bf16 pk[8];
        #pragma unroll
        for (int u = 0; u < 8; ++u) pk[u] = T[d * 65 + cc * 8 + u];
        *(uint4*)(vt + ((size_t)bh * HD_ + d) * S_ + t0 + cc * 8) = *(uint4*)pk;
    }
}

// ---------------------------------------------------------------------------
// Flash attention, S^T formulation.
// Round-5: QBLK=128 (8 waves, each owning 16 q-rows), Q held in registers
// (S^T form: a wave only ever reads its own q-rows), K/V double-buffered via
// GLDS16 with pre-swizzled global source (r4, verified), T13 defer-max
// (skip alpha-rescale unless per-q max grew by >8). LDS 48KB -> 3 blocks/CU.
// ---------------------------------------------------------------------------
#define AST 64

__global__ __launch_bounds__(512, 6)
void attn_flash(const __bf16* __restrict__ qkv, const __bf16* __restrict__ vt,
                __bf16* __restrict__ out)
{
    __shared__ __bf16 Ks[2][64 * AST];   // 2 x 8KB
    __shared__ __bf16 Vs[2][64 * AST];   // 2 x 8KB
    __shared__ __bf16 Ps[128 * AST];     // 16KB

    const int tid  = threadIdx.x;
    const int lane = tid & 63;
    const int wv   = tid >> 6;           // 0..7
    const int quad = lane >> 4;
    const int l15  = lane & 15;

    // grid = (8, 128): 8 s-blocks per head. Each XCD gets 128 contiguous k
    // = 16 whole heads -> K/V L2-resident per XCD.
    const int id = blockIdx.y * gridDim.x + blockIdx.x;
    const int k  = (id & 7) * ((S_ / 128) * B_ * H_ / 8) + (id >> 3);
    const int s0 = (k & 7) * 128;
    const int bh = k >> 3;
    const int b  = bh & (B_ - 1);
    const int h  = bh / B_;

    // K/V tile 0 via GLDS16: c = tid (512 chunks = 64 rows x 8 slots).
    // LDS dest linear; global slot pre-swizzled (cc ^ (row&7)).
    {
        int i = tid >> 3, cc = tid & 7;
        int scc = cc ^ (i & 7);
        GLDS16(qkv + (size_t)(i * B_ + b) * QKV_N + D_ + h * HD_ + scc * 8,
               (char*)(Ks[0]) + tid * 16);
        GLDS16(vt + ((size_t)bh * HD_ + i) * S_ + scc * 8,
               (char*)(Vs[0]) + tid * 16);
    }

    // Q in registers: this wave's q-row, both 32-wide K-halves.
    const int qrow = wv * 16 + l15;      // 0..127 within block
    bf16x8 bq[2];
    #pragma unroll
    for (int kk = 0; kk < 2; ++kk)
        bq[kk] = *(const bf16x8*)(qkv + (size_t)((s0 + qrow) * B_ + b) * QKV_N
                                  + h * HD_ + kk * 32 + quad * 8);

    __syncthreads();   // implicit vmcnt(0): K0/V0 landed

    f32x4 oacc[4] = {};
    float m_run = -1e30f, l_run = 0.f;
    const float C2    = 0.125f * 1.44269504f;
    const float LOG2E = 1.44269504f;

    const int nt = S_ / 64;
    for (int it = 0; it < nt; ++it) {
        const int cur = it & 1;

        // issue next tile's K/V loads; they fly across this tile's compute.
        if (it + 1 < nt) {
            const int t1 = (it + 1) * 64;
            int i = tid >> 3, cc = tid & 7;
            int scc = cc ^ (i & 7);
            GLDS16(qkv + (size_t)((t1 + i) * B_ + b) * QKV_N + D_ + h * HD_ + scc * 8,
                   (char*)(Ks[cur ^ 1]) + tid * 16);
            GLDS16(vt + ((size_t)bh * HD_ + i) * S_ + t1 + scc * 8,
                   (char*)(Vs[cur ^ 1]) + tid * 16);
        }

        // QK^T (S^T: lane holds 16 k's for q-col = l15)
        f32x4 sacc[4] = {};
        #pragma unroll
        for (int kk = 0; kk < 2; ++kk) {
            #pragma unroll
            for (int j = 0; j < 4; ++j) {
                int krow = j * 16 + l15;
                bf16x8 ak = *(const bf16x8*)(&Ks[cur][krow * AST + (((kk * 4 + quad) ^ (krow & 7)) * 8)]);
                sacc[j] = __builtin_amdgcn_mfma_f32_16x16x32_bf16(ak, bq[kk], sacc[j], 0, 0, 0);
            }
        }

        float mx = sacc[0][0];
        #pragma unroll
        for (int j = 0; j < 4; ++j)
            #pragma unroll
            for (int r = 0; r < 4; ++r) mx = fmaxf(mx, sacc[j][r]);
        mx = fmaxf(mx, __shfl_xor(mx, 16, 64));
        mx = fmaxf(mx, __shfl_xor(mx, 32, 64));
        float pm = mx * 0.125f;

        // T13 defer-max: only rescale when some q's max grew by >8 (nat-log
        // units). Skipped path leaves P bounded by e^8 ~ 2980 (bf16-safe).
        if (!__all(pm - m_run <= 8.0f)) {
            float mnew  = fmaxf(m_run, pm);
            float alpha = __builtin_amdgcn_exp2f((m_run - mnew) * LOG2E);
            l_run *= alpha;
            #pragma unroll
            for (int r = 0; r < 4; ++r) {
                float ar = __shfl(alpha, quad * 4 + r, 64);
                #pragma unroll
                for (int jd = 0; jd < 4; ++jd) oacc[jd][r] *= ar;
            }
            m_run = mnew;
        }

        float k1 = m_run * LOG2E;
        float rs = 0.f;
        #pragma unroll
        for (int j = 0; j < 4; ++j)
            #pragma unroll
            for (int r = 0; r < 4; ++r) {
                float p = __builtin_amdgcn_exp2f(sacc[j][r] * C2 - k1);
                sacc[j][r] = p;
                rs += p;
            }
        rs += __shfl_xor(rs, 16, 64);
        rs += __shfl_xor(rs, 32, 64);
        l_run += rs;

        // P write (swizzled, verified r3/r4): col block j -> 16B slot
        // (j*2+(quad>>1))^(qrow&7), 8B half quad&1. Rows are wave-private.
        #pragma unroll
        for (int j = 0; j < 4; ++j) {
            __bf16 pk[4] = {(__bf16)sacc[j][0], (__bf16)sacc[j][1],
                            (__bf16)sacc[j][2], (__bf16)sacc[j][3]};
            int s16 = (j * 2 + (quad >> 1)) ^ (qrow & 7);
            *(uint2*)(Ps + qrow * AST + s16 * 8 + (quad & 1) * 4) = *(uint2*)pk;
        }

        // PV (Ps rows wave-private: no barrier needed between write and read)
        #pragma unroll
        for (int kk = 0; kk < 2; ++kk) {
            bf16x8 ap = *(const bf16x8*)(Ps + qrow * AST + (((kk * 4 + quad) ^ (qrow & 7)) * 8));
            #pragma unroll
            for (int jd = 0; jd < 4; ++jd) {
                int vrow = jd * 16 + l15;
                bf16x8 bv = *(const bf16x8*)(&Vs[cur][vrow * AST + (((kk * 4 + quad) ^ (vrow & 7)) * 8)]);
                oacc[jd] = __builtin_amdgcn_mfma_f32_16x16x32_bf16(ap, bv, oacc[jd], 0, 0, 0);
            }
        }

        // single barrier per tile: drains vmcnt (next K/V landed) and orders
        // this tile's LDS reads before iter it+1 overwrites buf cur.
        __syncthreads();
    }

    float linv = 1.f / l_run;
    #pragma unroll
    for (int r = 0; r < 4; ++r) {
        float lr = __shfl(linv, quad * 4 + r, 64);
        int s = s0 + wv * 16 + quad * 4 + r;
        #pragma unroll
        for (int jd = 0; jd < 4; ++jd) {
            int d = jd * 16 + l15;
            out[(size_t)(s * B_ + b) * D_ + h * HD_ + d] = (__bf16)(oacc[jd][r] * lr);
        }
    }
}

// ---------------------------------------------------------------------------
// LayerNorm( xa + p0 + p1 + bias[col] ) * g + beta -> yout fp32 (+ ybf bf16)
// ---------------------------------------------------------------------------
__global__ __launch_bounds__(256)
void ln_res3(const float* __restrict__ xa, const __bf16* __restrict__ p0,
             const __bf16* __restrict__ p1, const float* __restrict__ bias,
             const float* __restrict__ g, const float* __restrict__ beta,
             float* __restrict__ yout, __bf16* __restrict__ ybf)
{
    __shared__ float red[8];
    const int row = blockIdx.x;
    const int tid = threadIdx.x;
    const size_t base = (size_t)row * D_ + tid * 4;

    float4 a  = *(const float4*)(xa + base);
    bf16x4 q0 = *(const bf16x4*)(p0 + base);
    bf16x4 q1 = *(const bf16x4*)(p1 + base);
    float4 bb = *(const float4*)(bias + tid * 4);
    float x0 = a.x + (float)q0[0] + (float)q1[0] + bb.x;
    float x1 = a.y + (float)q0[1] + (float)q1[1] + bb.y;
    float x2 = a.z + (float)q0[2] + (float)q1[2] + bb.z;
    float x3 = a.w + (float)q0[3] + (float)q1[3] + bb.w;

    float s  = x0 + x1 + x2 + x3;
    float ss = x0 * x0 + x1 * x1 + x2 * x2 + x3 * x3;
    for (int msk = 1; msk <= 32; msk <<= 1) {
        s  += __shfl_xor(s,  msk, 64);
        ss += __shfl_xor(ss, msk, 64);
    }
    const int wv = tid >> 6;
    if ((tid & 63) == 0) { red[wv] = s; red[4 + wv] = ss; }
    __syncthreads();
    s  = red[0] + red[1] + red[2] + red[3];
    ss = red[4] + red[5] + red[6] + red[7];
    float mean = s * (1.f / D_);
    float var  = ss * (1.f / D_) - mean * mean;
    float rstd = rsqrtf(var + 1e-5f);

    float4 gv = *(const float4*)(g + tid * 4);
    float4 bv = *(const float4*)(beta + tid * 4);
    float y0 = (x0 - mean) * rstd * gv.x + bv.x;
    float y1 = (x1 - mean) * rstd * gv.y + bv.y;
    float y2 = (x2 - mean) * rstd * gv.z + bv.z;
    float y3 = (x3 - mean) * rstd * gv.w + bv.w;
    *(float4*)(yout + base) = make_float4(y0, y1, y2, y3);
    if (ybf) {
        __bf16 t[4] = {(__bf16)y0, (__bf16)y1, (__bf16)y2, (__bf16)y3};
        *(uint2*)(ybf + base) = *(uint2*)t;
    }
}

// ---------------------------------------------------------------------------
extern "C" void kernel_launch(void* const* d_in, const int* in_sizes, int n_in,
                              void* d_out, int out_size, void* d_ws, size_t ws_size,
                              hipStream_t stream)
{
    const float* src       = (const float*)d_in[0];
    const float* in_proj_w = (const float*)d_in[1];
    const float* in_proj_b = (const float*)d_in[2];
    const float* out_w     = (const float*)d_in[3];
    const float* out_b     = (const float*)d_in[4];
    const float* lin1_w    = (const float*)d_in[5];
    const float* lin1_b    = (const float*)d_in[6];
    const float* lin2_w    = (const float*)d_in[7];
    const float* lin2_b    = (const float*)d_in[8];
    const float* n1_g = (const float*)d_in[9];
    const float* n1_b = (const float*)d_in[10];
    const float* n2_g = (const float*)d_in[11];
    const float* n2_b = (const float*)d_in[12];

    char* ws = (char*)d_ws;
    size_t off = 0;
    auto alloc = [&](size_t bytes) { char* p = ws + off; off += (bytes + 255) & ~(size_t)255; return p; };

    __bf16* src_bf = (__bf16*)alloc((size_t)M_ * D_ * 2);      // -> attn_o after QKV GEMM
    __bf16* w1     = (__bf16*)alloc((size_t)QKV_N * D_ * 2);
    __bf16* w2     = (__bf16*)alloc((size_t)D_ * D_ * 2);
    __bf16* w3     = (__bf16*)alloc((size_t)DFF_ * D_ * 2);
    __bf16* w4     = (__bf16*)alloc((size_t)D_ * DFF_ * 2);
    __bf16* qkv    = (__bf16*)alloc((size_t)M_ * QKV_N * 2);   // 48MB
    char*   h_r    = alloc((size_t)M_ * DFF_ * 2);             // 64MB: o0,o1 then hbf
    __bf16* xbf    = (__bf16*)alloc((size_t)M_ * D_ * 2);      // x bf16; -> f1 after lin1
    float*  xf     = (float*)alloc((size_t)M_ * D_ * 4);
    __bf16* vt     = (__bf16*)alloc((size_t)B_ * H_ * HD_ * S_ * 2); // 16MB; -> f0 after attn

    const size_t PART = (size_t)M_ * D_;   // 8M elems = 16MB bf16
    __bf16* attn_o = src_bf;               // src_bf dead after QKV GEMM
    __bf16* o0 = (__bf16*)h_r;             // outproj split-K partials (die at LN1)
    __bf16* o1 = o0 + PART;
    __bf16* hbf = (__bf16*)h_r;            // lin1 out (after LN1)
    __bf16* f0 = vt;                       // lin2 partials
    __bf16* f1 = xbf;                      // xbf dead after lin1

    const size_t SHM = 3 * 2 * 8192 * sizeof(__bf16);   // 96 KB ring LDS

    // 1) all fp32->bf16 conversions
    cvt_all<<<(CB4 + 255) / 256, 256, 0, stream>>>(
        src, in_proj_w, out_w, lin1_w, lin2_w, src_bf, w1, w2, w3, w4);

    // 2) QKV projection: qkv = src*W1^T + b   [8192,3072] bf16
    gemm256<true, false, true, false><<<dim3(M_ / 256, QKV_N / 256), 512, SHM, stream>>>(
        src_bf, w1, in_proj_b, qkv, nullptr, QKV_N, D_, D_);

    // 3) V transpose -> vt[bh][d][t]
    v_transpose<<<dim3(S_ / 64, B_ * H_), 256, 0, stream>>>(qkv, vt);

    // 4) attention -> attn_o bf16  (QBLK=128: grid (8,128), 512 thr)
    attn_flash<<<dim3(S_ / 128, B_ * H_), 512, 0, stream>>>(qkv, vt, attn_o);

    // 5) out projection, split-K x2 (Kloop=512): o0/o1 bf16 partials
    gemm256<true, false, false, true><<<dim3(M_ / 256, D_ / 256, 2), 512, SHM, stream>>>(
        attn_o, w2, nullptr, o0, o1, D_, D_ / 2, D_);

    // 6) x = LN(src + o0 + o1 + out_b) -> xf fp32, xbf bf16
    ln_res3<<<M_, 256, 0, stream>>>(src, o0, o1, out_b, n1_g, n1_b, xf, xbf);

    // 7) h = relu(x*W3^T + b3)  bf16 [8192,4096]
    gemm256<true, true, true, false><<<dim3(M_ / 256, DFF_ / 256), 512, SHM, stream>>>(
        xbf, w3, lin1_b, hbf, nullptr, DFF_, D_, D_);

    // 8) lin2, split-K x2 (Kloop=2048): f0/f1 bf16 partials
    gemm256<true, false, false, true><<<dim3(M_ / 256, D_ / 256, 2), 512, SHM, stream>>>(
        hbf, w4, nullptr, f0, f1, D_, DFF_ / 2, DFF_);

    // 9) out = LN(xf + f0 + f1 + lin2_b)  fp32
    ln_res3<<<M_, 256, 0, stream>>>(xf, f0, f1, lin2_b, n2_g, n2_b, (float*)d_out, nullptr);
}

// Round 6
// 457.932 us; speedup vs baseline: 1.2062x; 1.0164x over previous
//
#include <hip/hip_runtime.h>
#include <cstdint>
#include <cstddef>

// ---- sizes (compile-time for this problem) ----
#define S_  1024
#define B_  8
#define D_  1024
#define H_  16
#define HD_ 64
#define DFF_ 4096
#define M_  (S_*B_)      // 8192 rows
#define QKV_N (3*D_)     // 3072

typedef float f32x4 __attribute__((ext_vector_type(4)));
typedef __bf16 bf16x8 __attribute__((ext_vector_type(8)));
typedef __bf16 bf16x4 __attribute__((ext_vector_type(4)));

#define GLDS16(gp, lp) __builtin_amdgcn_global_load_lds( \
    (__attribute__((address_space(1))) void*)(gp), \
    (__attribute__((address_space(3))) void*)(lp), 16, 0, 0)

// ---------------------------------------------------------------------------
// fused fp32 -> bf16 conversion of all 5 tensors in one launch
// ---------------------------------------------------------------------------
#define CB0 (M_*D_/4)
#define CB1 (CB0 + QKV_N*D_/4)
#define CB2 (CB1 + D_*D_/4)
#define CB3 (CB2 + DFF_*D_/4)
#define CB4 (CB3 + D_*DFF_/4)

__global__ __launch_bounds__(256)
void cvt_all(const float* __restrict__ src, const float* __restrict__ w1f,
             const float* __restrict__ w2f, const float* __restrict__ w3f,
             const float* __restrict__ w4f,
             __bf16* __restrict__ src_bf, __bf16* __restrict__ w1,
             __bf16* __restrict__ w2, __bf16* __restrict__ w3,
             __bf16* __restrict__ w4)
{
    int i = blockIdx.x * 256 + threadIdx.x;
    const float* in; __bf16* out; int off;
    if      (i < CB0) { in = src; out = src_bf; off = 0;   }
    else if (i < CB1) { in = w1f; out = w1;     off = CB0; }
    else if (i < CB2) { in = w2f; out = w2;     off = CB1; }
    else if (i < CB3) { in = w3f; out = w3;     off = CB2; }
    else if (i < CB4) { in = w4f; out = w4;     off = CB3; }
    else return;
    int j = i - off;
    float4 v = *(const float4*)(in + (size_t)j * 4);
    __bf16 t[4] = {(__bf16)v.x, (__bf16)v.y, (__bf16)v.z, (__bf16)v.w};
    *(uint2*)(out + (size_t)j * 4) = *(uint2*)t;
}

// ---------------------------------------------------------------------------
// GEMM: C = A[M,K]*W[N,K]^T (+bias). 256x256 tile, 8 waves (2x4).
// Round-6: 8-phase schedule (m201 port). BK=64, 2 LDS buffers (128 KB),
// 4 phases per K-tile: {ds_read subtile; issue 1 stage chunk (2 GLDS16);
// barrier; lgkm(0); 16 MFMA w/ setprio; barrier}. Region-pipelined staging:
// chunk (matrix, kk-panel, row-half) of tile t+2 lands in the slot freed by
// tile t one phase after its last read. Counted waits (per-thread ledger):
//   W1 (end ph1) = vmcnt(10): drains exactly the kk1 chunks of tile t
//                  (B01,B11 issued t-2 ph3; A01,A11 issued t-1 ph0).
//   W2 (end ph3) = vmcnt(10): drains kk0 chunks of tile t+1.
// Tail: nt-2 -> vmcnt(8)/(4); nt-1 -> vmcnt(0)/(0).
// LDS layout per buffer: A,B each 2 panels [256][32] bf16; source-side XOR
// swizzle (slot ^ (row>>1)&3) -> conflict-free ds_read_b128 (r2, verified).
// ---------------------------------------------------------------------------
template<bool OUT_BF16, bool RELU, bool ADD_BIAS, bool SPLITZ>
__global__ __launch_bounds__(512, 2)
void gemm256(const __bf16* __restrict__ A, const __bf16* __restrict__ W,
             const float* __restrict__ bias,
             void* __restrict__ Cv0, void* __restrict__ Cv1,
             int N, int Kloop, int lda)
{
    extern __shared__ __bf16 lds[];   // 2 bufs x (A 2x[256][32] + B 2x[256][32])

    const int tid  = threadIdx.x;
    const int lane = tid & 63;
    const int wv   = tid >> 6;          // 0..7
    const int quad = lane >> 4;
    const int l15  = lane & 15;
    const int wm   = (wv >> 2) * 128;   // 0 / 128
    const int wn   = (wv & 3) * 64;     // 0 / 64 / 128 / 192

    // chunked raster + XCD-contiguous assignment (all grids: nwg%32==0, GM%8==0)
    const int id  = blockIdx.y * gridDim.x + blockIdx.x;
    const int nwg = gridDim.x * gridDim.y;
    const int q8  = nwg >> 3;
    const int k   = (id & 7) * q8 + (id >> 3);
    const int within = k & 31;
    const int chunk  = k >> 5;
    const int nchm   = gridDim.x >> 3;
    const int cm     = chunk % nchm;
    const int cn     = chunk / nchm;
    const int m0 = (cm * 8 + (within & 7)) * 256;
    const int n0 = (cn * 4 + (within >> 3)) * 256;

    void* Cv = Cv0;
    if (SPLITZ) {
        const int koff = blockIdx.z * Kloop;
        A += koff;
        W += koff;
        if (blockIdx.z) Cv = Cv1;
    }

    const int nt = Kloop >> 6;          // K-tiles of 64 (all uses: nt >= 8)

    // ---- chunk staging: 8KB = 128 rows x 32 cols of one panel, 1 GLDS16/thr
    const int crow = tid >> 2;                        // 0..127
    const int csl  = (tid & 3) ^ ((crow >> 1) & 3);   // source-side swizzle

    // byte offsets in LDS: buf 65536, B-matrix +32768, panel(kv) 16384, half 8192
    #define CHA(kv, hh, kt) GLDS16( \
        A + (size_t)(m0 + (hh) * 128 + crow) * lda + ((kt) << 6) + (kv) * 32 + csl * 8, \
        (char*)lds + (((kt) & 1) * 65536 + (kv) * 16384 + (hh) * 8192) + tid * 16)
    #define CHB(kv, hh, kt) GLDS16( \
        W + (size_t)(n0 + (hh) * 128 + crow) * lda + ((kt) << 6) + (kv) * 32 + csl * 8, \
        (char*)lds + (((kt) & 1) * 65536 + 32768 + (kv) * 16384 + (hh) * 8192) + tid * 16)

    // ---- prologue: tile0 (8 chunks) + tile1 (first 6) in steady-state order
    CHB(0,0,0); CHB(0,1,0); CHA(0,0,0); CHA(0,1,0);
    CHB(1,0,0); CHB(1,1,0); CHA(1,0,0); CHA(1,1,0);
    CHB(0,0,1); CHB(0,1,1); CHA(0,0,1); CHA(0,1,1);
    CHB(1,0,1); CHB(1,1,1);
    asm volatile("s_waitcnt vmcnt(6)" ::: "memory");   // tile0 landed; tile1's 6 fly
    __builtin_amdgcn_s_barrier();
    __builtin_amdgcn_sched_barrier(0);

    f32x4 acc[8][4] = {};

    // element offsets for reads: buf 32768, B +16384, panel(kk) 8192, row 32
    #define RD_A(dst, ii, kkp, CUR) { \
        int ra = wm + (ii) * 16 + l15; \
        dst = *(const bf16x8*)(lds + (CUR) + (kkp) * 8192 + ra * 32 + ((quad ^ ((ra >> 1) & 3)) * 8)); }
    #define RD_B(dst, jj, kkp, CUR) { \
        int rb = wn + (jj) * 16 + l15; \
        dst = *(const bf16x8*)(lds + (CUR) + 16384 + (kkp) * 8192 + rb * 32 + ((quad ^ ((rb >> 1) & 3)) * 8)); }

    #define PHASE_SYNC() \
        __builtin_amdgcn_sched_barrier(0); \
        __builtin_amdgcn_s_barrier(); \
        asm volatile("s_waitcnt lgkmcnt(0)" ::: "memory"); \
        __builtin_amdgcn_sched_barrier(0)

    #define KTILE(T, S1, S2, VM1, VM2) do { \
        const int cur = ((T) & 1) * 32768; \
        bf16x8 b_[4], a_[4]; \
        /* ---- phase 0: (i 0-3, kk0); stage A01,A11[T+1] ---- */ \
        _Pragma("unroll") for (int j = 0; j < 4; ++j) RD_B(b_[j], j, 0, cur); \
        _Pragma("unroll") for (int i = 0; i < 4; ++i) RD_A(a_[i], i, 0, cur); \
        if (S1) { CHA(1,0,(T)+1); CHA(1,1,(T)+1); } \
        PHASE_SYNC(); \
        __builtin_amdgcn_s_setprio(1); \
        _Pragma("unroll") for (int i = 0; i < 4; ++i) \
            _Pragma("unroll") for (int j = 0; j < 4; ++j) \
                acc[i][j] = __builtin_amdgcn_mfma_f32_16x16x32_bf16(a_[i], b_[j], acc[i][j], 0, 0, 0); \
        __builtin_amdgcn_s_setprio(0); \
        __builtin_amdgcn_sched_barrier(0); \
        __builtin_amdgcn_s_barrier(); \
        /* ---- phase 1: (i 4-7, kk0); stage B00,B10[T+2]; W1 ---- */ \
        _Pragma("unroll") for (int i = 0; i < 4; ++i) RD_A(a_[i], i + 4, 0, cur); \
        if (S2) { CHB(0,0,(T)+2); CHB(0,1,(T)+2); } \
        PHASE_SYNC(); \
        __builtin_amdgcn_s_setprio(1); \
        _Pragma("unroll") for (int i = 0; i < 4; ++i) \
            _Pragma("unroll") for (int j = 0; j < 4; ++j) \
                acc[i+4][j] = __builtin_amdgcn_mfma_f32_16x16x32_bf16(a_[i], b_[j], acc[i+4][j], 0, 0, 0); \
        __builtin_amdgcn_s_setprio(0); \
        asm volatile("s_waitcnt vmcnt(" VM1 ")" ::: "memory"); \
        __builtin_amdgcn_sched_barrier(0); \
        __builtin_amdgcn_s_barrier(); \
        /* ---- phase 2: (i 0-3, kk1); stage A00,A10[T+2] ---- */ \
        _Pragma("unroll") for (int j = 0; j < 4; ++j) RD_B(b_[j], j, 1, cur); \
        _Pragma("unroll") for (int i = 0; i < 4; ++i) RD_A(a_[i], i, 1, cur); \
        if (S2) { CHA(0,0,(T)+2); CHA(0,1,(T)+2); } \
        PHASE_SYNC(); \
        __builtin_amdgcn_s_setprio(1); \
        _Pragma("unroll") for (int i = 0; i < 4; ++i) \
            _Pragma("unroll") for (int j = 0; j < 4; ++j) \
                acc[i][j] = __builtin_amdgcn_mfma_f32_16x16x32_bf16(a_[i], b_[j], acc[i][j], 0, 0, 0); \
        __builtin_amdgcn_s_setprio(0); \
        __builtin_amdgcn_sched_barrier(0); \
        __builtin_amdgcn_s_barrier(); \
        /* ---- phase 3: (i 4-7, kk1); stage B01,B11[T+2]; W2 ---- */ \
        _Pragma("unroll") for (int i = 0; i < 4; ++i) RD_A(a_[i], i + 4, 1, cur); \
        if (S2) { CHB(1,0,(T)+2); CHB(1,1,(T)+2); } \
        PHASE_SYNC(); \
        __builtin_amdgcn_s_setprio(1); \
        _Pragma("unroll") for (int i = 0; i < 4; ++i) \
            _Pragma("unroll") for (int j = 0; j < 4; ++j) \
                acc[i+4][j] = __builtin_amdgcn_mfma_f32_16x16x32_bf16(a_[i], b_[j], acc[i+4][j], 0, 0, 0); \
        __builtin_amdgcn_s_setprio(0); \
        asm volatile("s_waitcnt vmcnt(" VM2 ")" ::: "memory"); \
        __builtin_amdgcn_sched_barrier(0); \
        __builtin_amdgcn_s_barrier(); \
    } while (0)

    for (int t = 0; t < nt - 2; ++t) KTILE(t, true, true, "10", "10");
    KTILE(nt - 2, true,  false, "8", "4");
    KTILE(nt - 1, false, false, "0", "0");

    #undef KTILE
    #undef PHASE_SYNC
    #undef RD_A
    #undef RD_B
    #undef CHA
    #undef CHB

    // epilogue: row = m0+wm+i*16+quad*4+r ; col = n0+wn+j*16+l15.
    // j innermost: 4 back-to-back 32B stores complete each 128B line.
    float bvj[4];
    #pragma unroll
    for (int j = 0; j < 4; ++j)
        bvj[j] = ADD_BIAS ? bias[n0 + wn + j * 16 + l15] : 0.f;
    #pragma unroll
    for (int i = 0; i < 8; ++i) {
        const int rbase = m0 + wm + i * 16 + quad * 4;
        #pragma unroll
        for (int r = 0; r < 4; ++r) {
            #pragma unroll
            for (int j = 0; j < 4; ++j) {
                const int col = n0 + wn + j * 16 + l15;
                float v = acc[i][j][r] + bvj[j];
                if (RELU) v = fmaxf(v, 0.f);
                if (OUT_BF16)
                    ((__bf16*)Cv)[(size_t)(rbase + r) * N + col] = (__bf16)v;
                else
                    ((float*)Cv)[(size_t)(rbase + r) * N + col] = v;
            }
        }
    }
}

// ---------------------------------------------------------------------------
// V transpose: qkv V-part -> vt[bh][d][t]
// ---------------------------------------------------------------------------
__global__ __launch_bounds__(256)
void v_transpose(const __bf16* __restrict__ qkv, __bf16* __restrict__ vt)
{
    __shared__ __bf16 T[64 * 65];
    const int tid = threadIdx.x;
    const int t0  = blockIdx.x * 64;
    const int bh  = blockIdx.y;
    const int b   = bh & (B_ - 1);
    const int h   = bh / B_;

    #pragma unroll
    for (int j = 0; j < 2; ++j) {
        int c = j * 256 + tid;
        int i = c >> 3, cc = c & 7;
        const __bf16* g = qkv + (size_t)((t0 + i) * B_ + b) * QKV_N + 2 * D_ + h * HD_ + cc * 8;
        bf16x8 v = *(const bf16x8*)g;
        #pragma unroll
        for (int u = 0; u < 8; ++u) T[(cc * 8 + u) * 65 + i] = v[u];
    }
    __syncthreads();
    #pragma unroll
    for (int j = 0; j < 2; ++j) {
        int c = j * 256 + tid;
        int d = c >> 3, cc = c & 7;
        __bf16 pk[8];
        #pragma unroll
        for (int u = 0; u < 8; ++u) pk[u] = T[d * 65 + cc * 8 + u];
        *(uint4*)(vt + ((size_t)bh * HD_ + d) * S_ + t0 + cc * 8) = *(uint4*)pk;
    }
}

// ---------------------------------------------------------------------------
// Flash attention, S^T formulation (round-5 structure, verified).
// ---------------------------------------------------------------------------
#define AST 64

__global__ __launch_bounds__(512, 6)
void attn_flash(const __bf16* __restrict__ qkv, const __bf16* __restrict__ vt,
                __bf16* __restrict__ out)
{
    __shared__ __bf16 Ks[2][64 * AST];   // 2 x 8KB
    __shared__ __bf16 Vs[2][64 * AST];   // 2 x 8KB
    __shared__ __bf16 Ps[128 * AST];     // 16KB

    const int tid  = threadIdx.x;
    const int lane = tid & 63;
    const int wv   = tid >> 6;           // 0..7
    const int quad = lane >> 4;
    const int l15  = lane & 15;

    // grid = (8, 128): each XCD gets 128 contiguous k = 16 whole heads.
    const int id = blockIdx.y * gridDim.x + blockIdx.x;
    const int k  = (id & 7) * ((S_ / 128) * B_ * H_ / 8) + (id >> 3);
    const int s0 = (k & 7) * 128;
    const int bh = k >> 3;
    const int b  = bh & (B_ - 1);
    const int h  = bh / B_;

    // K/V tile 0 via GLDS16 (linear dest, pre-swizzled global source)
    {
        int i = tid >> 3, cc = tid & 7;
        int scc = cc ^ (i & 7);
        GLDS16(qkv + (size_t)(i * B_ + b) * QKV_N + D_ + h * HD_ + scc * 8,
               (char*)(Ks[0]) + tid * 16);
        GLDS16(vt + ((size_t)bh * HD_ + i) * S_ + scc * 8,
               (char*)(Vs[0]) + tid * 16);
    }

    // Q in registers: this wave's q-row, both 32-wide K-halves.
    const int qrow = wv * 16 + l15;      // 0..127 within block
    bf16x8 bq[2];
    #pragma unroll
    for (int kk = 0; kk < 2; ++kk)
        bq[kk] = *(const bf16x8*)(qkv + (size_t)((s0 + qrow) * B_ + b) * QKV_N
                                  + h * HD_ + kk * 32 + quad * 8);

    __syncthreads();   // implicit vmcnt(0): K0/V0 landed

    f32x4 oacc[4] = {};
    float m_run = -1e30f, l_run = 0.f;
    const float C2    = 0.125f * 1.44269504f;
    const float LOG2E = 1.44269504f;

    const int nt = S_ / 64;
    for (int it = 0; it < nt; ++it) {
        const int cur = it & 1;

        if (it + 1 < nt) {
            const int t1 = (it + 1) * 64;
            int i = tid >> 3, cc = tid & 7;
            int scc = cc ^ (i & 7);
            GLDS16(qkv + (size_t)((t1 + i) * B_ + b) * QKV_N + D_ + h * HD_ + scc * 8,
                   (char*)(Ks[cur ^ 1]) + tid * 16);
            GLDS16(vt + ((size_t)bh * HD_ + i) * S_ + t1 + scc * 8,
                   (char*)(Vs[cur ^ 1]) + tid * 16);
        }

        f32x4 sacc[4] = {};
        #pragma unroll
        for (int kk = 0; kk < 2; ++kk) {
            #pragma unroll
            for (int j = 0; j < 4; ++j) {
                int krow = j * 16 + l15;
                bf16x8 ak = *(const bf16x8*)(&Ks[cur][krow * AST + (((kk * 4 + quad) ^ (krow & 7)) * 8)]);
                sacc[j] = __builtin_amdgcn_mfma_f32_16x16x32_bf16(ak, bq[kk], sacc[j], 0, 0, 0);
            }
        }

        float mx = sacc[0][0];
        #pragma unroll
        for (int j = 0; j < 4; ++j)
            #pragma unroll
            for (int r = 0; r < 4; ++r) mx = fmaxf(mx, sacc[j][r]);
        mx = fmaxf(mx, __shfl_xor(mx, 16, 64));
        mx = fmaxf(mx, __shfl_xor(mx, 32, 64));
        float pm = mx * 0.125f;

        if (!__all(pm - m_run <= 8.0f)) {
            float mnew  = fmaxf(m_run, pm);
            float alpha = __builtin_amdgcn_exp2f((m_run - mnew) * LOG2E);
            l_run *= alpha;
            #pragma unroll
            for (int r = 0; r < 4; ++r) {
                float ar = __shfl(alpha, quad * 4 + r, 64);
                #pragma unroll
                for (int jd = 0; jd < 4; ++jd) oacc[jd][r] *= ar;
            }
            m_run = mnew;
        }

        float k1 = m_run * LOG2E;
        float rs = 0.f;
        #pragma unroll
        for (int j = 0; j < 4; ++j)
            #pragma unroll
            for (int r = 0; r < 4; ++r) {
                float p = __builtin_amdgcn_exp2f(sacc[j][r] * C2 - k1);
                sacc[j][r] = p;
                rs += p;
            }
        rs += __shfl_xor(rs, 16, 64);
        rs += __shfl_xor(rs, 32, 64);
        l_run += rs;

        #pragma unroll
        for (int j = 0; j < 4; ++j) {
            __bf16 pk[4] = {(__bf16)sacc[j][0], (__bf16)sacc[j][1],
                            (__bf16)sacc[j][2], (__bf16)sacc[j][3]};
            int s16 = (j * 2 + (quad >> 1)) ^ (qrow & 7);
            *(uint2*)(Ps + qrow * AST + s16 * 8 + (quad & 1) * 4) = *(uint2*)pk;
        }

        #pragma unroll
        for (int kk = 0; kk < 2; ++kk) {
            bf16x8 ap = *(const bf16x8*)(Ps + qrow * AST + (((kk * 4 + quad) ^ (qrow & 7)) * 8));
            #pragma unroll
            for (int jd = 0; jd < 4; ++jd) {
                int vrow = jd * 16 + l15;
                bf16x8 bv = *(const bf16x8*)(&Vs[cur][vrow * AST + (((kk * 4 + quad) ^ (vrow & 7)) * 8)]);
                oacc[jd] = __builtin_amdgcn_mfma_f32_16x16x32_bf16(ap, bv, oacc[jd], 0, 0, 0);
            }
        }

        __syncthreads();
    }

    float linv = 1.f / l_run;
    #pragma unroll
    for (int r = 0; r < 4; ++r) {
        float lr = __shfl(linv, quad * 4 + r, 64);
        int s = s0 + wv * 16 + quad * 4 + r;
        #pragma unroll
        for (int jd = 0; jd < 4; ++jd) {
            int d = jd * 16 + l15;
            out[(size_t)(s * B_ + b) * D_ + h * HD_ + d] = (__bf16)(oacc[jd][r] * lr);
        }
    }
}

// ---------------------------------------------------------------------------
// LayerNorm( xa + p0 + p1 + bias[col] ) * g + beta -> yout fp32 (+ ybf bf16)
// ---------------------------------------------------------------------------
__global__ __launch_bounds__(256)
void ln_res3(const float* __restrict__ xa, const __bf16* __restrict__ p0,
             const __bf16* __restrict__ p1, const float* __restrict__ bias,
             const float* __restrict__ g, const float* __restrict__ beta,
             float* __restrict__ yout, __bf16* __restrict__ ybf)
{
    __shared__ float red[8];
    const int row = blockIdx.x;
    const int tid = threadIdx.x;
    const size_t base = (size_t)row * D_ + tid * 4;

    float4 a  = *(const float4*)(xa + base);
    bf16x4 q0 = *(const bf16x4*)(p0 + base);
    bf16x4 q1 = *(const bf16x4*)(p1 + base);
    float4 bb = *(const float4*)(bias + tid * 4);
    float x0 = a.x + (float)q0[0] + (float)q1[0] + bb.x;
    float x1 = a.y + (float)q0[1] + (float)q1[1] + bb.y;
    float x2 = a.z + (float)q0[2] + (float)q1[2] + bb.z;
    float x3 = a.w + (float)q0[3] + (float)q1[3] + bb.w;

    float s  = x0 + x1 + x2 + x3;
    float ss = x0 * x0 + x1 * x1 + x2 * x2 + x3 * x3;
    for (int msk = 1; msk <= 32; msk <<= 1) {
        s  += __shfl_xor(s,  msk, 64);
        ss += __shfl_xor(ss, msk, 64);
    }
    const int wv = tid >> 6;
    if ((tid & 63) == 0) { red[wv] = s; red[4 + wv] = ss; }
    __syncthreads();
    s  = red[0] + red[1] + red[2] + red[3];
    ss = red[4] + red[5] + red[6] + red[7];
    float mean = s * (1.f / D_);
    float var  = ss * (1.f / D_) - mean * mean;
    float rstd = rsqrtf(var + 1e-5f);

    float4 gv = *(const float4*)(g + tid * 4);
    float4 bv = *(const float4*)(beta + tid * 4);
    float y0 = (x0 - mean) * rstd * gv.x + bv.x;
    float y1 = (x1 - mean) * rstd * gv.y + bv.y;
    float y2 = (x2 - mean) * rstd * gv.z + bv.z;
    float y3 = (x3 - mean) * rstd * gv.w + bv.w;
    *(float4*)(yout + base) = make_float4(y0, y1, y2, y3);
    if (ybf) {
        __bf16 t[4] = {(__bf16)y0, (__bf16)y1, (__bf16)y2, (__bf16)y3};
        *(uint2*)(ybf + base) = *(uint2*)t;
    }
}

// ---------------------------------------------------------------------------
extern "C" void kernel_launch(void* const* d_in, const int* in_sizes, int n_in,
                              void* d_out, int out_size, void* d_ws, size_t ws_size,
                              hipStream_t stream)
{
    const float* src       = (const float*)d_in[0];
    const float* in_proj_w = (const float*)d_in[1];
    const float* in_proj_b = (const float*)d_in[2];
    const float* out_w     = (const float*)d_in[3];
    const float* out_b     = (const float*)d_in[4];
    const float* lin1_w    = (const float*)d_in[5];
    const float* lin1_b    = (const float*)d_in[6];
    const float* lin2_w    = (const float*)d_in[7];
    const float* lin2_b    = (const float*)d_in[8];
    const float* n1_g = (const float*)d_in[9];
    const float* n1_b = (const float*)d_in[10];
    const float* n2_g = (const float*)d_in[11];
    const float* n2_b = (const float*)d_in[12];

    char* ws = (char*)d_ws;
    size_t off = 0;
    auto alloc = [&](size_t bytes) { char* p = ws + off; off += (bytes + 255) & ~(size_t)255; return p; };

    __bf16* src_bf = (__bf16*)alloc((size_t)M_ * D_ * 2);      // -> attn_o after QKV GEMM
    __bf16* w1     = (__bf16*)alloc((size_t)QKV_N * D_ * 2);
    __bf16* w2     = (__bf16*)alloc((size_t)D_ * D_ * 2);
    __bf16* w3     = (__bf16*)alloc((size_t)DFF_ * D_ * 2);
    __bf16* w4     = (__bf16*)alloc((size_t)D_ * DFF_ * 2);
    __bf16* qkv    = (__bf16*)alloc((size_t)M_ * QKV_N * 2);   // 48MB
    char*   h_r    = alloc((size_t)M_ * DFF_ * 2);             // 64MB: o0,o1 then hbf
    __bf16* xbf    = (__bf16*)alloc((size_t)M_ * D_ * 2);      // x bf16; -> f1 after lin1
    float*  xf     = (float*)alloc((size_t)M_ * D_ * 4);
    __bf16* vt     = (__bf16*)alloc((size_t)B_ * H_ * HD_ * S_ * 2); // 16MB; -> f0 after attn

    const size_t PART = (size_t)M_ * D_;   // 8M elems = 16MB bf16
    __bf16* attn_o = src_bf;               // src_bf dead after QKV GEMM
    __bf16* o0 = (__bf16*)h_r;             // outproj split-K partials (die at LN1)
    __bf16* o1 = o0 + PART;
    __bf16* hbf = (__bf16*)h_r;            // lin1 out (after LN1)
    __bf16* f0 = vt;                       // lin2 partials
    __bf16* f1 = xbf;                      // xbf dead after lin1

    const size_t SHM = 131072;             // 128 KB: 2 dbuf x (A 32KB + B 32KB)

    // 1) all fp32->bf16 conversions
    cvt_all<<<(CB4 + 255) / 256, 256, 0, stream>>>(
        src, in_proj_w, out_w, lin1_w, lin2_w, src_bf, w1, w2, w3, w4);

    // 2) QKV projection: qkv = src*W1^T + b   [8192,3072] bf16
    gemm256<true, false, true, false><<<dim3(M_ / 256, QKV_N / 256), 512, SHM, stream>>>(
        src_bf, w1, in_proj_b, qkv, nullptr, QKV_N, D_, D_);

    // 3) V transpose -> vt[bh][d][t]
    v_transpose<<<dim3(S_ / 64, B_ * H_), 256, 0, stream>>>(qkv, vt);

    // 4) attention -> attn_o bf16  (QBLK=128: grid (8,128), 512 thr)
    attn_flash<<<dim3(S_ / 128, B_ * H_), 512, 0, stream>>>(qkv, vt, attn_o);

    // 5) out projection, split-K x2 (Kloop=512): o0/o1 bf16 partials
    gemm256<true, false, false, true><<<dim3(M_ / 256, D_ / 256, 2), 512, SHM, stream>>>(
        attn_o, w2, nullptr, o0, o1, D_, D_ / 2, D_);

    // 6) x = LN(src + o0 + o1 + out_b) -> xf fp32, xbf bf16
    ln_res3<<<M_, 256, 0, stream>>>(src, o0, o1, out_b, n1_g, n1_b, xf, xbf);

    // 7) h = relu(x*W3^T + b3)  bf16 [8192,4096]
    gemm256<true, true, true, false><<<dim3(M_ / 256, DFF_ / 256), 512, SHM, stream>>>(
        xbf, w3, lin1_b, hbf, nullptr, DFF_, D_, D_);

    // 8) lin2, split-K x2 (Kloop=2048): f0/f1 bf16 partials
    gemm256<true, false, false, true><<<dim3(M_ / 256, D_ / 256, 2), 512, SHM, stream>>>(
        hbf, w4, nullptr, f0, f1, D_, DFF_ / 2, DFF_);

    // 9) out = LN(xf + f0 + f1 + lin2_b)  fp32
    ln_res3<<<M_, 256, 0, stream>>>(xf, f0, f1, lin2_b, n2_g, n2_b, (float*)d_out, nullptr);
}